// Round 5
// baseline (438.906 us; speedup 1.0000x reference)
//
#include <hip/hip_runtime.h>

typedef _Float16 f16;
typedef f16 f16x8 __attribute__((ext_vector_type(8)));
typedef f16 f16x4 __attribute__((ext_vector_type(4)));
typedef float f32x4 __attribute__((ext_vector_type(4)));

#define S_LEN 2048
#define D_MODEL 2048
#define NHEADS 8
#define DQ 128
#define DV 256
#define NCOL 6144   // q(1024) | k(1024) | v(2048) | og(2048)
#define NROWS 4096  // B*S
#define CHUNK 64
#define NCHUNK 32   // per sequence

// ---------------- fused f32 -> f16 casts (x + all weights, one launch) ----------------
__global__ __launch_bounds__(256) void cast_all(const float* __restrict__ x,
                                                const float* __restrict__ Wq,
                                                const float* __restrict__ Wk,
                                                const float* __restrict__ Wv,
                                                const float* __restrict__ Wog,
                                                const float* __restrict__ Wout,
                                                f16* __restrict__ xf,
                                                f16* __restrict__ wcat,
                                                f16* __restrict__ woutf) {
    int i = blockIdx.x * 256 + threadIdx.x;   // float4 index
    const float* src;
    f16* dst;
    int local;
    if (i < 2097152)      { src = x;    dst = xf;                        local = i; }
    else if (i < 2621440) { src = Wq;   dst = wcat;                      local = i - 2097152; }
    else if (i < 3145728) { src = Wk;   dst = wcat + (size_t)2097152;    local = i - 2621440; }
    else if (i < 4194304) { src = Wv;   dst = wcat + (size_t)4194304;    local = i - 3145728; }
    else if (i < 5242880) { src = Wog;  dst = wcat + (size_t)8388608;    local = i - 4194304; }
    else                  { src = Wout; dst = woutf;                     local = i - 5242880; }
    float4 v = reinterpret_cast<const float4*>(src)[local];
    f16x4 o = { (f16)v.x, (f16)v.y, (f16)v.z, (f16)v.w };
    reinterpret_cast<f16x4*>(dst)[local] = o;
}

// ---------------- GEMM: C[M,N] = A[M,K] @ B[N,K]^T  (f16 in, OT out) ----------------
#define BK 32
template <typename OT>
__global__ __launch_bounds__(256) void gemm_f16(const f16* __restrict__ A,
                                                const f16* __restrict__ B,
                                                OT* __restrict__ C,
                                                int M, int N, int K, int ldc,
                                                int scale_cols, float scale) {
    __shared__ f16 As[128 * BK];   // 8 KB
    __shared__ f16 Bs[128 * BK];   // 8 KB
    const int tid  = threadIdx.x;
    const int lane = tid & 63;
    const int w    = tid >> 6;
    const int wr   = w >> 1, wc = w & 1;
    const int m0   = blockIdx.y * 128, n0 = blockIdx.x * 128;
    const int r16  = lane & 15;
    const int kg   = (lane >> 4) * 8;

    const int srow = tid >> 2;
    const int scol = (tid & 3) * 8;
    const f16* Ag = A + (size_t)(m0 + srow) * K + scol;
    const f16* Bg = B + (size_t)(n0 + srow) * K + scol;
    f16* As0 = &As[w * 512];
    f16* Bs0 = &Bs[w * 512];

    f32x4 acc[4][4];
#pragma unroll
    for (int i = 0; i < 4; i++)
#pragma unroll
        for (int j = 0; j < 4; j++) acc[i][j] = (f32x4){0.f, 0.f, 0.f, 0.f};

    for (int k0 = 0; k0 < K; k0 += BK) {
        __syncthreads();
        __builtin_amdgcn_global_load_lds(
            (const __attribute__((address_space(1))) void*)(Ag + k0),
            (__attribute__((address_space(3))) void*)(As0), 16, 0, 0);
        __builtin_amdgcn_global_load_lds(
            (const __attribute__((address_space(1))) void*)(Ag + (size_t)64 * K + k0),
            (__attribute__((address_space(3))) void*)(As0 + 2048), 16, 0, 0);
        __builtin_amdgcn_global_load_lds(
            (const __attribute__((address_space(1))) void*)(Bg + k0),
            (__attribute__((address_space(3))) void*)(Bs0), 16, 0, 0);
        __builtin_amdgcn_global_load_lds(
            (const __attribute__((address_space(1))) void*)(Bg + (size_t)64 * K + k0),
            (__attribute__((address_space(3))) void*)(Bs0 + 2048), 16, 0, 0);
        __syncthreads();

        f16x8 a[4], b[4];
#pragma unroll
        for (int i = 0; i < 4; i++)
            a[i] = *reinterpret_cast<const f16x8*>(&As[(wr * 64 + i * 16 + r16) * BK + kg]);
#pragma unroll
        for (int j = 0; j < 4; j++)
            b[j] = *reinterpret_cast<const f16x8*>(&Bs[(wc * 64 + j * 16 + r16) * BK + kg]);
#pragma unroll
        for (int i = 0; i < 4; i++)
#pragma unroll
            for (int j = 0; j < 4; j++)
                acc[i][j] = __builtin_amdgcn_mfma_f32_16x16x32_f16(a[i], b[j], acc[i][j], 0, 0, 0);
    }

    const int crow = m0 + wr * 64 + (lane >> 4) * 4;
    const int ccol = n0 + wc * 64 + r16;
#pragma unroll
    for (int i = 0; i < 4; i++) {
#pragma unroll
        for (int j = 0; j < 4; j++) {
            const int col = ccol + j * 16;
            const float sc = (col < scale_cols) ? scale : 1.f;
#pragma unroll
            for (int r = 0; r < 4; r++) {
                C[(size_t)(crow + i * 16 + r) * ldc + col] = (OT)(acc[i][j][r] * sc);
            }
        }
    }
}

// ---------------- gates: exact f32; stores (i_capped, log_sigmoid(f_capped)) ----------------
__global__ __launch_bounds__(256) void gate_kernel(const float* __restrict__ x,
                                                   const float* __restrict__ Wig,
                                                   const float* __restrict__ big,
                                                   const float* __restrict__ Wfg,
                                                   const float* __restrict__ bfg,
                                                   float* __restrict__ gates) {
    __shared__ float xs[4][D_MODEL];
    const int tid  = threadIdx.x;
    const int row0 = blockIdx.x * 4;
#pragma unroll
    for (int r = 0; r < 4; ++r) {
        const float4 v0 = *reinterpret_cast<const float4*>(&x[(size_t)(row0 + r) * D_MODEL + tid * 8]);
        const float4 v1 = *reinterpret_cast<const float4*>(&x[(size_t)(row0 + r) * D_MODEL + tid * 8 + 4]);
        *reinterpret_cast<float4*>(&xs[r][tid * 8])     = v0;
        *reinterpret_cast<float4*>(&xs[r][tid * 8 + 4]) = v1;
    }
    __syncthreads();

    const int o = tid >> 4;
    const int t = tid & 15;
    const int head = o & 7;
    const bool is_i = (o < 8);
    const float* W = (is_i ? Wig : Wfg) + (size_t)head * D_MODEL;

    float a0 = 0.f, a1 = 0.f, a2 = 0.f, a3 = 0.f;
    for (int j = t * 128; j < t * 128 + 128; j += 4) {
        const float4 wv = *reinterpret_cast<const float4*>(&W[j]);
        const float4 xa = *reinterpret_cast<const float4*>(&xs[0][j]);
        const float4 xb = *reinterpret_cast<const float4*>(&xs[1][j]);
        const float4 xc = *reinterpret_cast<const float4*>(&xs[2][j]);
        const float4 xd = *reinterpret_cast<const float4*>(&xs[3][j]);
        a0 += wv.x * xa.x + wv.y * xa.y + wv.z * xa.z + wv.w * xa.w;
        a1 += wv.x * xb.x + wv.y * xb.y + wv.z * xb.z + wv.w * xb.w;
        a2 += wv.x * xc.x + wv.y * xc.y + wv.z * xc.z + wv.w * xc.w;
        a3 += wv.x * xd.x + wv.y * xd.y + wv.z * xd.z + wv.w * xd.w;
    }
#pragma unroll
    for (int off = 1; off < 16; off <<= 1) {
        a0 += __shfl_xor(a0, off);
        a1 += __shfl_xor(a1, off);
        a2 += __shfl_xor(a2, off);
        a3 += __shfl_xor(a3, off);
    }
    if (t == 0) {
        const float bias = is_i ? big[head] : bfg[head];
        float accs[4] = {a0, a1, a2, a3};
#pragma unroll
        for (int r = 0; r < 4; ++r) {
            const float pre = accs[r] + bias;
            const float capped = 15.f * tanhf(pre * (1.f / 15.f));
            float val;
            if (is_i) val = capped;
            else      val = fminf(capped, 0.f) - log1pf(expf(-fabsf(capped)));
            gates[(size_t)(row0 + r) * 16 + head * 2 + (is_i ? 0 : 1)] = val;
        }
    }
}

// ---------------- gate scan: per (b,h) max-plus scan, chunk decomposition ----------------
__global__ __launch_bounds__(64) void gate_scan(const float* __restrict__ gates,
                                                float4* __restrict__ gs4,
                                                float2* __restrict__ gchunk,
                                                float* __restrict__ mf) {
    const int bh = blockIdx.x;
    const int b = bh >> 3, h = bh & 7;
    const int l = threadIdx.x;
    __shared__ float2 comp[NCHUNK];
    if (l < NCHUNK) {
        const float* gp = gates + ((size_t)b * S_LEN + l * CHUNK) * 16 + h * 2;
        float bsum = 0.f, r = -1e30f;
        for (int s = 0; s < CHUNK; s++) {
            float2 g = *reinterpret_cast<const float2*>(gp + (size_t)s * 16);
            bsum += g.y;
            r = fmaxf(r, g.x - bsum);
        }
        comp[l] = make_float2(bsum, r);
    }
    __syncthreads();
    if (l < NCHUNK) {
        float m0 = 0.f;
        for (int c = 0; c < l; c++) m0 = comp[c].x + fmaxf(m0, comp[c].y);
        const float* gp = gates + ((size_t)b * S_LEN + l * CHUNK) * 16 + h * 2;
        float4* out = gs4 + (size_t)bh * S_LEN + l * CHUNK;
        float bsum = 0.f, r = -1e30f;
        float mlast = 0.f, Alast = 0.f, alast = 0.f;
        for (int s = 0; s < CHUNK; s++) {
            float2 g = *reinterpret_cast<const float2*>(gp + (size_t)s * 16);
            bsum += g.y;
            const float uu = g.x - bsum;
            r = fmaxf(r, uu);
            const float mx = fmaxf(m0, r);
            const float mt = bsum + mx;
            const float At = -mx;
            const float al = expf(m0 + At);
            out[s] = make_float4(uu, At, al, expf(-mt));
            if (s == CHUNK - 1) { mlast = mt; Alast = At; alast = al; }
        }
        gchunk[bh * NCHUNK + l] = make_float2(alast, Alast);
        if (l == NCHUNK - 1) mf[bh] = mlast;
    }
}

// ---------------- phase A: per (bh, chunk) intra attention + chunk summaries ----------------
// S^T = mfma(K, Q); P = exp(A_t + u_s) .* S (s<=t); h_intra = P @ V; U = (gamma K)^T @ V;
// Un[dq] = sum_s KgT[dq][s]  (n-recurrence increment)
__global__ __launch_bounds__(256) void phaseA(const f16* __restrict__ qkvo,
                                              const float4* __restrict__ gs4,
                                              float* __restrict__ qn_intra,
                                              f16* __restrict__ Ubuf,
                                              f16* __restrict__ hintraT,
                                              float* __restrict__ UnB) {
    __shared__ f16 Kn[64][136];     // K natural [s][dq]  (dq = 0..127, +8 pad)
    __shared__ f16 KgT[128][72];    // gamma-scaled K^T [dq][s]
    __shared__ f16 VT[256][72];     // V^T [v][s]
    __shared__ f16 Pl[64][72];      // P [t][s]
    __shared__ float u_s[64], A_t[64];
    __shared__ float qnp[4][64];

    const int bid = blockIdx.x;
    const int bh = bid >> 5, ck = bid & 31;
    const int b = bh >> 3, h = bh & 7;
    const int tid = threadIdx.x;
    const int w = tid >> 6, l = tid & 63;

    const size_t rowbase = (size_t)b * S_LEN + ck * CHUNK;

    if (tid < 64) {
        float4 g = gs4[(size_t)bh * S_LEN + ck * CHUNK + tid];
        u_s[tid] = g.x; A_t[tid] = g.y;
    }
    const int sK = tid & 63, quad = tid >> 6;
    f16x8 kreg[4];
    {
        const f16* kp = qkvo + (rowbase + sK) * NCOL + 1024 + h * 128 + quad * 32;
#pragma unroll
        for (int i = 0; i < 4; i++) kreg[i] = *reinterpret_cast<const f16x8*>(kp + i * 8);
#pragma unroll
        for (int i = 0; i < 4; i++) *reinterpret_cast<f16x8*>(&Kn[sK][quad * 32 + i * 8]) = kreg[i];
    }
    {
        const f16* vp = qkvo + (rowbase + sK) * NCOL + 2048 + h * 256 + quad * 64;
#pragma unroll
        for (int i = 0; i < 8; i++) {
            f16x8 v = *reinterpret_cast<const f16x8*>(vp + i * 8);
#pragma unroll
            for (int e = 0; e < 8; e++) VT[quad * 64 + i * 8 + e][sK] = v[e];
        }
    }
    __syncthreads();
    {
        const float gam = __expf(u_s[sK] + A_t[63]);
#pragma unroll
        for (int i = 0; i < 4; i++)
#pragma unroll
            for (int e = 0; e < 8; e++)
                KgT[quad * 32 + i * 8 + e][sK] = (f16)(gam * (float)kreg[i][e]);
    }
    // S^T mfma
    f16x8 af[4];
#pragma unroll
    for (int kk = 0; kk < 4; kk++)
        af[kk] = *reinterpret_cast<const f16x8*>(&Kn[w * 16 + (l & 15)][kk * 32 + (l >> 4) * 8]);
    f32x4 st[4];
#pragma unroll
    for (int ct = 0; ct < 4; ct++) {
        st[ct] = (f32x4){0.f, 0.f, 0.f, 0.f};
#pragma unroll
        for (int kk = 0; kk < 4; kk++) {
            const f16* qp = qkvo + (rowbase + ct * 16 + (l & 15)) * NCOL + h * 128 + kk * 32 + (l >> 4) * 8;
            f16x8 bf = *reinterpret_cast<const f16x8*>(qp);
            st[ct] = __builtin_amdgcn_mfma_f32_16x16x32_f16(af[kk], bf, st[ct], 0, 0, 0);
        }
    }
#pragma unroll
    for (int ct = 0; ct < 4; ct++) {
        const int tloc = ct * 16 + (l & 15);
        const float At = A_t[tloc];
        float part = 0.f;
        f16x4 pk;
#pragma unroll
        for (int i = 0; i < 4; i++) {
            const int sloc = w * 16 + (l >> 4) * 4 + i;
            const float val = (sloc <= tloc) ? st[ct][i] * __expf(At + u_s[sloc]) : 0.f;
            part += val;
            pk[i] = (f16)val;
        }
        part += __shfl_xor(part, 16);
        part += __shfl_xor(part, 32);
        if ((l >> 4) == 0) qnp[w][tloc] = part;
        *reinterpret_cast<f16x4*>(&Pl[tloc][w * 16 + (l >> 4) * 4]) = pk;
    }
    __syncthreads();
    if (tid < 64)
        qn_intra[(size_t)bh * S_LEN + ck * CHUNK + tid] =
            qnp[0][tid] + qnp[1][tid] + qnp[2][tid] + qnp[3][tid];
    // PV
    {
        f16x8 pa[2];
#pragma unroll
        for (int kk = 0; kk < 2; kk++)
            pa[kk] = *reinterpret_cast<const f16x8*>(&Pl[w * 16 + (l & 15)][kk * 32 + (l >> 4) * 8]);
#pragma unroll
        for (int vt = 0; vt < 16; vt++) {
            f32x4 acc = (f32x4){0.f, 0.f, 0.f, 0.f};
#pragma unroll
            for (int kk = 0; kk < 2; kk++) {
                f16x8 vb = *reinterpret_cast<const f16x8*>(&VT[vt * 16 + (l & 15)][kk * 32 + (l >> 4) * 8]);
                acc = __builtin_amdgcn_mfma_f32_16x16x32_f16(pa[kk], vb, acc, 0, 0, 0);
            }
            f16x4 hk;
#pragma unroll
            for (int i = 0; i < 4; i++) hk[i] = (f16)acc[i];
            const size_t addr = ((size_t)bh * 256 + vt * 16 + (l & 15)) * S_LEN
                              + ck * CHUNK + w * 16 + (l >> 4) * 4;
            *reinterpret_cast<f16x4*>(&hintraT[addr]) = hk;
        }
    }
    // U (chunk summary, stored [dv][dq])
#pragma unroll
    for (int q = 0; q < 4; q++) {
        const int dvt = w * 4 + q;
        f16x8 vb[2];
#pragma unroll
        for (int kk = 0; kk < 2; kk++)
            vb[kk] = *reinterpret_cast<const f16x8*>(&VT[dvt * 16 + (l & 15)][kk * 32 + (l >> 4) * 8]);
#pragma unroll
        for (int dqt = 0; dqt < 8; dqt++) {
            f32x4 acc = (f32x4){0.f, 0.f, 0.f, 0.f};
#pragma unroll
            for (int kk = 0; kk < 2; kk++) {
                f16x8 ka = *reinterpret_cast<const f16x8*>(&KgT[dqt * 16 + (l & 15)][kk * 32 + (l >> 4) * 8]);
                acc = __builtin_amdgcn_mfma_f32_16x16x32_f16(ka, vb[kk], acc, 0, 0, 0);
            }
            f16x4 uk;
#pragma unroll
            for (int i = 0; i < 4; i++) uk[i] = (f16)acc[i];
            const size_t addr = (((size_t)bh * NCHUNK + ck) * 256 + dvt * 16 + (l & 15)) * 128
                              + dqt * 16 + (l >> 4) * 4;
            *reinterpret_cast<f16x4*>(&Ubuf[addr]) = uk;
        }
    }
    // Un row-sums: Un[dq] = sum_s KgT[dq][s]  (f32)
    {
        const int dq = tid >> 1, half = tid & 1;
        float sum = 0.f;
#pragma unroll
        for (int i = 0; i < 4; i++) {
            f16x8 kv = *reinterpret_cast<const f16x8*>(&KgT[dq][half * 32 + i * 8]);
#pragma unroll
            for (int e = 0; e < 8; e++) sum += (float)kv[e];
        }
        sum += __shfl_xor(sum, 1);
        if (half == 0) UnB[((size_t)bh * NCHUNK + ck) * 128 + dq] = sum;
    }
}

// ---------------- phase B: inter-chunk C and n recurrences + output ----------------
__global__ __launch_bounds__(256) void phaseB(const f16* __restrict__ qkvo,
                                              const f16* __restrict__ Ubuf,
                                              const f16* __restrict__ hintraT,
                                              const float4* __restrict__ gs4,
                                              const float2* __restrict__ gchunk,
                                              const float* __restrict__ qn_intra,
                                              const float* __restrict__ UnB,
                                              f16* __restrict__ hbuf,
                                              float* __restrict__ Cf,
                                              float* __restrict__ nf) {
    const int bid = blockIdx.x;
    const int bh = bid >> 4, vt = bid & 15;
    const int b = bh >> 3, h = bh & 7;
    const int tid = threadIdx.x, w = tid >> 6, l = tid & 63;
    const int dv = vt * 16 + (l & 15);

    float c[4][8];
    float nn[4][8];   // replicated n-state (dq-indexed, dv-independent)
#pragma unroll
    for (int kk = 0; kk < 4; kk++)
#pragma unroll
        for (int j = 0; j < 8; j++) { c[kk][j] = 0.f; nn[kk][j] = 0.f; }

    for (int ck = 0; ck < NCHUNK; ck++) {
        // U fragments (match C's B-frag layout)
        f16x8 uf[4];
        const f16* ub = Ubuf + (((size_t)bh * NCHUNK + ck) * 256 + dv) * 128 + (l >> 4) * 8;
#pragma unroll
        for (int kk = 0; kk < 4; kk++) uf[kk] = *reinterpret_cast<const f16x8*>(ub + kk * 32);
        // Un (f32, replicated across dv)
        float un[4][8];
        const float* unp = UnB + ((size_t)bh * NCHUNK + ck) * 128 + (l >> 4) * 8;
#pragma unroll
        for (int kk = 0; kk < 4; kk++) {
            const float4 u0 = *reinterpret_cast<const float4*>(unp + kk * 32);
            const float4 u1 = *reinterpret_cast<const float4*>(unp + kk * 32 + 4);
            un[kk][0] = u0.x; un[kk][1] = u0.y; un[kk][2] = u0.z; un[kk][3] = u0.w;
            un[kk][4] = u1.x; un[kk][5] = u1.y; un[kk][6] = u1.z; un[kk][7] = u1.w;
        }
        // Q fragments
        const int t0 = ck * CHUNK + w * 16;
        f16x8 af[4];
        const f16* qp = qkvo + ((size_t)b * S_LEN + t0 + (l & 15)) * NCOL + h * 128 + (l >> 4) * 8;
#pragma unroll
        for (int kk = 0; kk < 4; kk++) af[kk] = *reinterpret_cast<const f16x8*>(qp + kk * 32);
        // C,n -> f16 B-frags; H = Q @ C_in; Hn = Q . n_in
        f16x8 cf[4], cfn[4];
#pragma unroll
        for (int kk = 0; kk < 4; kk++)
#pragma unroll
            for (int j = 0; j < 8; j++) { cf[kk][j] = (f16)c[kk][j]; cfn[kk][j] = (f16)nn[kk][j]; }
        f32x4 H  = (f32x4){0.f, 0.f, 0.f, 0.f};
        f32x4 Hn = (f32x4){0.f, 0.f, 0.f, 0.f};
#pragma unroll
        for (int kk = 0; kk < 4; kk++) {
            H  = __builtin_amdgcn_mfma_f32_16x16x32_f16(af[kk], cf[kk],  H,  0, 0, 0);
            Hn = __builtin_amdgcn_mfma_f32_16x16x32_f16(af[kk], cfn[kk], Hn, 0, 0, 0);
        }
        // epilogue: qn = qn_intra + alpha*Hn; rden; h = (h_intra + alpha*H)*rden
        const int tt = t0 + (l >> 4) * 4;
        f16x4 hi = *reinterpret_cast<const f16x4*>(&hintraT[((size_t)bh * 256 + dv) * S_LEN + tt]);
        const float4 qnI = *reinterpret_cast<const float4*>(&qn_intra[(size_t)bh * S_LEN + tt]);
        const float qni[4] = {qnI.x, qnI.y, qnI.z, qnI.w};
#pragma unroll
        for (int i = 0; i < 4; i++) {
            const float4 g = gs4[(size_t)bh * S_LEN + tt + i];
            const float al = g.z;
            const float qn = qni[i] + al * Hn[i];
            const float rd = 1.f / (fmaxf(fabsf(qn), g.w) + 1e-6f);
            const float hval = ((float)hi[i] + al * H[i]) * rd;
            hbuf[((size_t)b * S_LEN + tt + i) * D_MODEL + h * 256 + dv] = (f16)hval;
        }
        // C = F*C + U; n = F*n + Un
        const float F = gchunk[bh * NCHUNK + ck].x;
#pragma unroll
        for (int kk = 0; kk < 4; kk++)
#pragma unroll
            for (int j = 0; j < 8; j++) {
                c[kk][j]  = fmaf(F, c[kk][j],  (float)uf[kk][j]);
                nn[kk][j] = fmaf(F, nn[kk][j], un[kk][j]);
            }
    }
    if (w == 0) {
#pragma unroll
        for (int kk = 0; kk < 4; kk++)
#pragma unroll
            for (int j = 0; j < 8; j++) {
                const int dq = kk * 32 + (l >> 4) * 8 + j;
                Cf[((size_t)bh * 128 + dq) * 256 + dv] = c[kk][j];
            }
        if (vt == 0 && (l & 15) == 0) {
#pragma unroll
            for (int kk = 0; kk < 4; kk++)
#pragma unroll
                for (int j = 0; j < 8; j++) {
                    const int dq = kk * 32 + (l >> 4) * 8 + j;
                    nf[(size_t)bh * 128 + dq] = nn[kk][j];
                }
        }
    }
}

// ---------------- per-head layernorm * gamma * sigmoid(og), f16 in/out ----------------
__global__ __launch_bounds__(256) void norm_kernel(const f16* __restrict__ hbuf,
                                                   const f16* __restrict__ qkvo,
                                                   const float* __restrict__ gamma,
                                                   f16* __restrict__ hout) {
    const int row = blockIdx.x;
    const int tid = threadIdx.x;
    const int g = tid >> 5;
    const int l = tid & 31;
    const f16* hrow = hbuf + (size_t)row * D_MODEL + g * 256 + l * 8;
    f16x8 hv8 = *reinterpret_cast<const f16x8*>(hrow);
    float hv[8];
#pragma unroll
    for (int e = 0; e < 8; e++) hv[e] = (float)hv8[e];
    float s = 0.f, s2 = 0.f;
#pragma unroll
    for (int e = 0; e < 8; e++) { s += hv[e]; s2 += hv[e] * hv[e]; }
#pragma unroll
    for (int off = 1; off < 32; off <<= 1) {
        s  += __shfl_xor(s, off);
        s2 += __shfl_xor(s2, off);
    }
    const float mu  = s * (1.f / 256.f);
    const float var = s2 * (1.f / 256.f) - mu * mu;
    const float rs  = rsqrtf(var + 1e-6f);
    const f16* ogr = qkvo + (size_t)row * NCOL + 4096 + g * 256 + l * 8;
    f16x8 og8 = *reinterpret_cast<const f16x8*>(ogr);
    const float* gam = gamma + g * 256 + l * 8;
    f16x8 o;
#pragma unroll
    for (int e = 0; e < 8; e++) {
        const float og  = (float)og8[e];
        const float sig = __builtin_amdgcn_rcpf(1.f + __expf(-og));
        const float hn  = (hv[e] - mu) * rs * gam[e];
        o[e] = (f16)(sig * hn);
    }
    *reinterpret_cast<f16x8*>(&hout[(size_t)row * D_MODEL + g * 256 + l * 8]) = o;
}

// ---------------- launch ----------------
extern "C" void kernel_launch(void* const* d_in, const int* in_sizes, int n_in,
                              void* d_out, int out_size, void* d_ws, size_t ws_size,
                              hipStream_t stream) {
    (void)in_sizes; (void)n_in; (void)out_size; (void)ws_size;
    const float* x     = (const float*)d_in[0];
    const float* Wq    = (const float*)d_in[1];
    const float* Wk    = (const float*)d_in[2];
    const float* Wv    = (const float*)d_in[3];
    const float* Wog   = (const float*)d_in[4];
    const float* Wig   = (const float*)d_in[5];
    const float* big   = (const float*)d_in[6];
    const float* Wfg   = (const float*)d_in[7];
    const float* bfg   = (const float*)d_in[8];
    const float* gamma = (const float*)d_in[9];
    const float* Wout  = (const float*)d_in[10];

    char* ws = (char*)d_ws;
    size_t off = 0;
    f16*    xf     = (f16*)(ws + off);    off += (size_t)NROWS * D_MODEL * 2;
    f16*    wcat   = (f16*)(ws + off);    off += (size_t)NCOL * D_MODEL * 2;
    f16*    woutf  = (f16*)(ws + off);    off += (size_t)D_MODEL * D_MODEL * 2;
    f16*    qkvo   = (f16*)(ws + off);    off += (size_t)NROWS * NCOL * 2;
    float*  gates  = (float*)(ws + off);  off += (size_t)NROWS * 16 * 4;
    float4* gs4    = (float4*)(ws + off); off += (size_t)16 * S_LEN * 16;
    float2* gchunk = (float2*)(ws + off); off += (size_t)16 * NCHUNK * 8;
    float*  qn_i   = (float*)(ws + off);  off += (size_t)16 * S_LEN * 4;
    float*  UnB    = (float*)(ws + off);  off += (size_t)16 * NCHUNK * 128 * 4;
    f16*    Ubuf   = (f16*)(ws + off);    off += (size_t)16 * NCHUNK * 256 * 128 * 2;
    f16*    hinT   = (f16*)(ws + off);    off += (size_t)16 * 256 * S_LEN * 2;
    f16*    hbuf   = (f16*)(ws + off);    off += (size_t)NROWS * D_MODEL * 2;
    f16*    houtf  = xf;  // xf dead after GEMM1

    float* y  = (float*)d_out;
    float* Cf = y + (size_t)NROWS * D_MODEL;
    float* nf = Cf + (size_t)16 * 128 * 256;
    float* mf = nf + (size_t)16 * 128;

    // fused casts (x + all weights)
    cast_all<<<24576, 256, 0, stream>>>(x, Wq, Wk, Wv, Wog, Wout, xf, wcat, woutf);

    // gates (exact f32) + chunk decomposition
    gate_kernel<<<NROWS / 4, 256, 0, stream>>>(x, Wig, big, Wfg, bfg, gates);
    gate_scan<<<16, 64, 0, stream>>>(gates, gs4, gchunk, mf);

    // fused qkvo projection (f16 out); q columns pre-scaled by DQ^-0.5
    gemm_f16<f16><<<dim3(NCOL / 128, NROWS / 128), 256, 0, stream>>>(
        xf, wcat, qkvo, NROWS, NCOL, D_MODEL, NCOL, 1024, 0.08838834764831845f);

    // chunkwise mLSTM
    phaseA<<<512, 256, 0, stream>>>(qkvo, gs4, qn_i, Ubuf, hinT, UnB);
    phaseB<<<256, 256, 0, stream>>>(qkvo, Ubuf, hinT, gs4, gchunk, qn_i, UnB, hbuf, Cf, nf);

    // multihead norm + output gate
    norm_kernel<<<NROWS, 256, 0, stream>>>(hbuf, qkvo, gamma, houtf);

    // y = h_out @ Wout^T
    gemm_f16<float><<<dim3(D_MODEL / 128, NROWS / 128), 256, 0, stream>>>(
        houtf, woutf, y, NROWS, D_MODEL, D_MODEL, D_MODEL, 0, 1.f);
}

// Round 6
// 430.065 us; speedup vs baseline: 1.0206x; 1.0206x over previous
//
#include <hip/hip_runtime.h>

typedef _Float16 f16;
typedef f16 f16x8 __attribute__((ext_vector_type(8)));
typedef f16 f16x4 __attribute__((ext_vector_type(4)));
typedef float f32x4 __attribute__((ext_vector_type(4)));

#define S_LEN 2048
#define D_MODEL 2048
#define NHEADS 8
#define DQ 128
#define DV 256
#define NCOL 6272   // q(1024) | k(1024) | v(2048) | og(2048) | ig(8)@6144 | fg(8)@6152 | pad->6272
#define QOFF 0
#define KOFF 1024
#define VOFF 2048
#define OGOFF 4096
#define IGOFF 6144
#define FGOFF 6152
#define NROWS 4096  // B*S
#define CHUNK 64
#define NCHUNK 32   // per sequence

// ---------------- fused f32 -> f16 casts (x + all weights incl. gates) ----------------
// float4-unit ranges (cumulative): x 2097152 | Wq 524288 | Wk 524288 | Wv 1048576 |
// Wog 1048576 | Wig 4096 | Wfg 4096 | Wout 1048576  => total 6299648 = 256*24608
__global__ __launch_bounds__(256) void cast_all(const float* __restrict__ x,
                                                const float* __restrict__ Wq,
                                                const float* __restrict__ Wk,
                                                const float* __restrict__ Wv,
                                                const float* __restrict__ Wog,
                                                const float* __restrict__ Wig,
                                                const float* __restrict__ Wfg,
                                                const float* __restrict__ Wout,
                                                f16* __restrict__ xf,
                                                f16* __restrict__ wcat,
                                                f16* __restrict__ woutf) {
    int i = blockIdx.x * 256 + threadIdx.x;   // float4 index
    const float* src;
    f16* dst;
    int local;
    if (i < 2097152)      { src = x;    dst = xf;                         local = i; }
    else if (i < 2621440) { src = Wq;   dst = wcat;                       local = i - 2097152; }
    else if (i < 3145728) { src = Wk;   dst = wcat + (size_t)2097152;     local = i - 2621440; }
    else if (i < 4194304) { src = Wv;   dst = wcat + (size_t)4194304;     local = i - 3145728; }
    else if (i < 5242880) { src = Wog;  dst = wcat + (size_t)8388608;     local = i - 4194304; }
    else if (i < 5246976) { src = Wig;  dst = wcat + (size_t)12582912;    local = i - 5242880; }
    else if (i < 5251072) { src = Wfg;  dst = wcat + (size_t)12599296;    local = i - 5246976; }
    else                  { src = Wout; dst = woutf;                      local = i - 5251072; }
    float4 v = reinterpret_cast<const float4*>(src)[local];
    f16x4 o = { (f16)v.x, (f16)v.y, (f16)v.z, (f16)v.w };
    reinterpret_cast<f16x4*>(dst)[local] = o;
}

// ---------------- GEMM: C[M,N] = A[M,K] @ B[N,K]^T  (f16 in, OT out) ----------------
// 128x128 tile, BK=64 (2 x 32-col LDS subtiles keep 64B read stride -> 8-way max),
// gload_lds staging, 2 barriers per 64-K step, 32 MFMA per step.
#define BK 64
template <typename OT>
__global__ __launch_bounds__(256) void gemm_f16(const f16* __restrict__ A,
                                                const f16* __restrict__ B,
                                                OT* __restrict__ C,
                                                int M, int N, int K, int ldc,
                                                int scale_cols, float scale) {
    __shared__ f16 As[2 * 128 * 32];   // [sub(k-half)][row][32]  16 KB
    __shared__ f16 Bs[2 * 128 * 32];   // 16 KB
    const int tid  = threadIdx.x;
    const int lane = tid & 63;
    const int w    = tid >> 6;
    const int wr   = w >> 1, wc = w & 1;
    const int m0   = blockIdx.y * 128, n0 = blockIdx.x * 128;
    const int r16  = lane & 15;
    const int kg   = (lane >> 4) * 8;

    // staging: one call = 4 waves x 1KB = 32 rows x 64 cols (both subtiles).
    // wave w: subtile w>>1 (k-cols (w>>1)*32..+31), rows (w&1)*16 + l/4, col (l&3)*8
    const int g_row = (w & 1) * 16 + (lane >> 2);
    const int g_col = (w >> 1) * 32 + (lane & 3) * 8;
    const f16* Ag = A + (size_t)(m0 + g_row) * K + g_col;
    const f16* Bg = B + (size_t)(n0 + g_row) * K + g_col;
    f16* As0 = &As[(w >> 1) * 4096 + (w & 1) * 512];
    f16* Bs0 = &Bs[(w >> 1) * 4096 + (w & 1) * 512];

    f32x4 acc[4][4];
#pragma unroll
    for (int i = 0; i < 4; i++)
#pragma unroll
        for (int j = 0; j < 4; j++) acc[i][j] = (f32x4){0.f, 0.f, 0.f, 0.f};

    for (int k0 = 0; k0 < K; k0 += BK) {
        __syncthreads();
#pragma unroll
        for (int c = 0; c < 4; c++)
            __builtin_amdgcn_global_load_lds(
                (const __attribute__((address_space(1))) void*)(Ag + (size_t)(c * 32) * K + k0),
                (__attribute__((address_space(3))) void*)(As0 + c * 1024), 16, 0, 0);
#pragma unroll
        for (int c = 0; c < 4; c++)
            __builtin_amdgcn_global_load_lds(
                (const __attribute__((address_space(1))) void*)(Bg + (size_t)(c * 32) * K + k0),
                (__attribute__((address_space(3))) void*)(Bs0 + c * 1024), 16, 0, 0);
        __syncthreads();

#pragma unroll
        for (int kk = 0; kk < 2; kk++) {
            f16x8 a[4], b[4];
#pragma unroll
            for (int i = 0; i < 4; i++)
                a[i] = *reinterpret_cast<const f16x8*>(&As[kk * 4096 + (wr * 64 + i * 16 + r16) * 32 + kg]);
#pragma unroll
            for (int j = 0; j < 4; j++)
                b[j] = *reinterpret_cast<const f16x8*>(&Bs[kk * 4096 + (wc * 64 + j * 16 + r16) * 32 + kg]);
#pragma unroll
            for (int i = 0; i < 4; i++)
#pragma unroll
                for (int j = 0; j < 4; j++)
                    acc[i][j] = __builtin_amdgcn_mfma_f32_16x16x32_f16(a[i], b[j], acc[i][j], 0, 0, 0);
        }
    }

    const int crow = m0 + wr * 64 + (lane >> 4) * 4;
    const int ccol = n0 + wc * 64 + r16;
#pragma unroll
    for (int i = 0; i < 4; i++) {
#pragma unroll
        for (int j = 0; j < 4; j++) {
            const int col = ccol + j * 16;
            const float sc = (col < scale_cols) ? scale : 1.f;
#pragma unroll
            for (int r = 0; r < 4; r++) {
                C[(size_t)(crow + i * 16 + r) * ldc + col] = (OT)(acc[i][j][r] * sc);
            }
        }
    }
}

// ---------------- gate scan: reads fused f16 preacts; max-plus scan, chunk decomposition ----------------
// gs4[bh][t] = (u_t, A_t, alpha_t, exp(-m_t)); gchunk[bh][j] = (F_j, G_j)
__global__ __launch_bounds__(64) void gate_scan(const f16* __restrict__ qkvo,
                                                const float* __restrict__ big,
                                                const float* __restrict__ bfg,
                                                float4* __restrict__ gs4,
                                                float2* __restrict__ gchunk,
                                                float* __restrict__ mf) {
    const int bh = blockIdx.x;
    const int b = bh >> 3, h = bh & 7;
    const int l = threadIdx.x;
    __shared__ float2 comp[NCHUNK];
    __shared__ float2 sif[S_LEN];   // (i_capped, f_log) per step, 16 KB
    if (l < NCHUNK) {
        const f16* gp = qkvo + ((size_t)b * S_LEN + l * CHUNK) * NCOL + IGOFF;
        const float bi = big[h], bff = bfg[h];
        float bsum = 0.f, r = -1e30f;
        for (int s = 0; s < CHUNK; s++) {
            const float ip = (float)gp[(size_t)s * NCOL + h] + bi;
            const float fp = (float)gp[(size_t)s * NCOL + 8 + h] + bff;
            const float ic = 15.f * tanhf(ip * (1.f / 15.f));
            const float fc = 15.f * tanhf(fp * (1.f / 15.f));
            const float flog = fminf(fc, 0.f) - log1pf(expf(-fabsf(fc)));
            sif[l * CHUNK + s] = make_float2(ic, flog);
            bsum += flog;
            r = fmaxf(r, ic - bsum);
        }
        comp[l] = make_float2(bsum, r);
    }
    __syncthreads();
    if (l < NCHUNK) {
        float m0 = 0.f;   // m at chunk start (initial state m = 0)
        for (int c = 0; c < l; c++) m0 = comp[c].x + fmaxf(m0, comp[c].y);
        float4* out = gs4 + (size_t)bh * S_LEN + l * CHUNK;
        float bsum = 0.f, r = -1e30f;
        float mlast = 0.f, Alast = 0.f, alast = 0.f;
        for (int s = 0; s < CHUNK; s++) {
            const float2 g = sif[l * CHUNK + s];
            bsum += g.y;
            const float uu = g.x - bsum;
            r = fmaxf(r, uu);
            const float mx = fmaxf(m0, r);
            const float mt = bsum + mx;
            const float At = -mx;
            const float al = expf(m0 + At);
            out[s] = make_float4(uu, At, al, expf(-mt));
            if (s == CHUNK - 1) { mlast = mt; Alast = At; alast = al; }
        }
        gchunk[bh * NCHUNK + l] = make_float2(alast, Alast);
        if (l == NCHUNK - 1) mf[bh] = mlast;
    }
}

// ---------------- phase A: per (bh, chunk) intra attention + chunk summaries ----------------
__global__ __launch_bounds__(256) void phaseA(const f16* __restrict__ qkvo,
                                              const float4* __restrict__ gs4,
                                              float* __restrict__ qn_intra,
                                              f16* __restrict__ Ubuf,
                                              f16* __restrict__ hintraT,
                                              float* __restrict__ UnB) {
    __shared__ f16 Kn[64][136];     // K natural [s][dq]  (+8 pad)
    __shared__ f16 Qn[64][136];     // Q natural [t][dq]  (+8 pad)
    __shared__ f16 KgT[128][72];    // gamma-scaled K^T [dq][s]
    __shared__ f16 VT[256][72];     // V^T [v][s]
    __shared__ f16 Pl[64][72];      // P [t][s]
    __shared__ float u_s[64], A_t[64];
    __shared__ float qnp[4][64];

    const int bid = blockIdx.x;
    const int bh = bid >> 5, ck = bid & 31;
    const int b = bh >> 3, h = bh & 7;
    const int tid = threadIdx.x;
    const int w = tid >> 6, l = tid & 63;

    const size_t rowbase = (size_t)b * S_LEN + ck * CHUNK;

    if (tid < 64) {
        float4 g = gs4[(size_t)bh * S_LEN + ck * CHUNK + tid];
        u_s[tid] = g.x; A_t[tid] = g.y;
    }
    const int sK = tid & 63, quad = tid >> 6;
    // stage K natural (keep regs for KgT) + Q natural
    f16x8 kreg[4];
    {
        const f16* kp = qkvo + (rowbase + sK) * NCOL + KOFF + h * 128 + quad * 32;
        const f16* qp = qkvo + (rowbase + sK) * NCOL + QOFF + h * 128 + quad * 32;
#pragma unroll
        for (int i = 0; i < 4; i++) kreg[i] = *reinterpret_cast<const f16x8*>(kp + i * 8);
#pragma unroll
        for (int i = 0; i < 4; i++) *reinterpret_cast<f16x8*>(&Kn[sK][quad * 32 + i * 8]) = kreg[i];
#pragma unroll
        for (int i = 0; i < 4; i++)
            *reinterpret_cast<f16x8*>(&Qn[sK][quad * 32 + i * 8]) =
                *reinterpret_cast<const f16x8*>(qp + i * 8);
    }
    // stage V^T
    {
        const f16* vp = qkvo + (rowbase + sK) * NCOL + VOFF + h * 256 + quad * 64;
#pragma unroll
        for (int i = 0; i < 8; i++) {
            f16x8 v = *reinterpret_cast<const f16x8*>(vp + i * 8);
#pragma unroll
            for (int e = 0; e < 8; e++) VT[quad * 64 + i * 8 + e][sK] = v[e];
        }
    }
    __syncthreads();
    // stage gamma-scaled K^T (gamma_s = exp(u_s + G), G = A_t[63])
    {
        const float gam = __expf(u_s[sK] + A_t[63]);
#pragma unroll
        for (int i = 0; i < 4; i++)
#pragma unroll
            for (int e = 0; e < 8; e++)
                KgT[quad * 32 + i * 8 + e][sK] = (f16)(gam * (float)kreg[i][e]);
    }
    // S^T mfma: A = Kn rows (wave's s-tile), B = Qn (LDS)
    f16x8 af[4];
#pragma unroll
    for (int kk = 0; kk < 4; kk++)
        af[kk] = *reinterpret_cast<const f16x8*>(&Kn[w * 16 + (l & 15)][kk * 32 + (l >> 4) * 8]);
    f32x4 st[4];
#pragma unroll
    for (int ct = 0; ct < 4; ct++) {
        st[ct] = (f32x4){0.f, 0.f, 0.f, 0.f};
#pragma unroll
        for (int kk = 0; kk < 4; kk++) {
            f16x8 bf = *reinterpret_cast<const f16x8*>(&Qn[ct * 16 + (l & 15)][kk * 32 + (l >> 4) * 8]);
            st[ct] = __builtin_amdgcn_mfma_f32_16x16x32_f16(af[kk], bf, st[ct], 0, 0, 0);
        }
    }
    // P^T: weights + mask; qn partials; write P to LDS (natural [t][s])
#pragma unroll
    for (int ct = 0; ct < 4; ct++) {
        const int tloc = ct * 16 + (l & 15);
        const float At = A_t[tloc];
        float part = 0.f;
        f16x4 pk;
#pragma unroll
        for (int i = 0; i < 4; i++) {
            const int sloc = w * 16 + (l >> 4) * 4 + i;
            const float val = (sloc <= tloc) ? st[ct][i] * __expf(At + u_s[sloc]) : 0.f;
            part += val;
            pk[i] = (f16)val;
        }
        part += __shfl_xor(part, 16);
        part += __shfl_xor(part, 32);
        if ((l >> 4) == 0) qnp[w][tloc] = part;
        *reinterpret_cast<f16x4*>(&Pl[tloc][w * 16 + (l >> 4) * 4]) = pk;
    }
    __syncthreads();
    if (tid < 64)
        qn_intra[(size_t)bh * S_LEN + ck * CHUNK + tid] =
            qnp[0][tid] + qnp[1][tid] + qnp[2][tid] + qnp[3][tid];
    // PV: h_intra(64x256), wave w -> t-tile w
    {
        f16x8 pa[2];
#pragma unroll
        for (int kk = 0; kk < 2; kk++)
            pa[kk] = *reinterpret_cast<const f16x8*>(&Pl[w * 16 + (l & 15)][kk * 32 + (l >> 4) * 8]);
#pragma unroll
        for (int vt = 0; vt < 16; vt++) {
            f32x4 acc = (f32x4){0.f, 0.f, 0.f, 0.f};
#pragma unroll
            for (int kk = 0; kk < 2; kk++) {
                f16x8 vb = *reinterpret_cast<const f16x8*>(&VT[vt * 16 + (l & 15)][kk * 32 + (l >> 4) * 8]);
                acc = __builtin_amdgcn_mfma_f32_16x16x32_f16(pa[kk], vb, acc, 0, 0, 0);
            }
            f16x4 hk;
#pragma unroll
            for (int i = 0; i < 4; i++) hk[i] = (f16)acc[i];
            const size_t addr = ((size_t)bh * 256 + vt * 16 + (l & 15)) * S_LEN
                              + ck * CHUNK + w * 16 + (l >> 4) * 4;
            *reinterpret_cast<f16x4*>(&hintraT[addr]) = hk;
        }
    }
    // U (chunk summary, stored [dv][dq]); wave w -> dv-tiles w*4..w*4+3
#pragma unroll
    for (int q = 0; q < 4; q++) {
        const int dvt = w * 4 + q;
        f16x8 vb[2];
#pragma unroll
        for (int kk = 0; kk < 2; kk++)
            vb[kk] = *reinterpret_cast<const f16x8*>(&VT[dvt * 16 + (l & 15)][kk * 32 + (l >> 4) * 8]);
#pragma unroll
        for (int dqt = 0; dqt < 8; dqt++) {
            f32x4 acc = (f32x4){0.f, 0.f, 0.f, 0.f};
#pragma unroll
            for (int kk = 0; kk < 2; kk++) {
                f16x8 ka = *reinterpret_cast<const f16x8*>(&KgT[dqt * 16 + (l & 15)][kk * 32 + (l >> 4) * 8]);
                acc = __builtin_amdgcn_mfma_f32_16x16x32_f16(ka, vb[kk], acc, 0, 0, 0);
            }
            f16x4 uk;
#pragma unroll
            for (int i = 0; i < 4; i++) uk[i] = (f16)acc[i];
            const size_t addr = (((size_t)bh * NCHUNK + ck) * 256 + dvt * 16 + (l & 15)) * 128
                              + dqt * 16 + (l >> 4) * 4;
            *reinterpret_cast<f16x4*>(&Ubuf[addr]) = uk;
        }
    }
    // Un row-sums: Un[dq] = sum_s KgT[dq][s]  (f32)
    {
        const int dq = tid >> 1, half = tid & 1;
        float sum = 0.f;
#pragma unroll
        for (int i = 0; i < 4; i++) {
            f16x8 kv = *reinterpret_cast<const f16x8*>(&KgT[dq][half * 32 + i * 8]);
#pragma unroll
            for (int e = 0; e < 8; e++) sum += (float)kv[e];
        }
        sum += __shfl_xor(sum, 1);
        if (half == 0) UnB[((size_t)bh * NCHUNK + ck) * 128 + dq] = sum;
    }
}

// ---------------- phase B: inter-chunk C and n recurrences + output ----------------
__global__ __launch_bounds__(256) void phaseB(const f16* __restrict__ qkvo,
                                              const f16* __restrict__ Ubuf,
                                              const f16* __restrict__ hintraT,
                                              const float4* __restrict__ gs4,
                                              const float2* __restrict__ gchunk,
                                              const float* __restrict__ qn_intra,
                                              const float* __restrict__ UnB,
                                              f16* __restrict__ hbuf,
                                              float* __restrict__ Cf,
                                              float* __restrict__ nf) {
    const int bid = blockIdx.x;
    const int bh = bid >> 4, vt = bid & 15;
    const int b = bh >> 3, h = bh & 7;
    const int tid = threadIdx.x, w = tid >> 6, l = tid & 63;
    const int dv = vt * 16 + (l & 15);

    float c[4][8];
    float nn[4][8];
#pragma unroll
    for (int kk = 0; kk < 4; kk++)
#pragma unroll
        for (int j = 0; j < 8; j++) { c[kk][j] = 0.f; nn[kk][j] = 0.f; }

    for (int ck = 0; ck < NCHUNK; ck++) {
        f16x8 uf[4];
        const f16* ub = Ubuf + (((size_t)bh * NCHUNK + ck) * 256 + dv) * 128 + (l >> 4) * 8;
#pragma unroll
        for (int kk = 0; kk < 4; kk++) uf[kk] = *reinterpret_cast<const f16x8*>(ub + kk * 32);
        float un[4][8];
        const float* unp = UnB + ((size_t)bh * NCHUNK + ck) * 128 + (l >> 4) * 8;
#pragma unroll
        for (int kk = 0; kk < 4; kk++) {
            const float4 u0 = *reinterpret_cast<const float4*>(unp + kk * 32);
            const float4 u1 = *reinterpret_cast<const float4*>(unp + kk * 32 + 4);
            un[kk][0] = u0.x; un[kk][1] = u0.y; un[kk][2] = u0.z; un[kk][3] = u0.w;
            un[kk][4] = u1.x; un[kk][5] = u1.y; un[kk][6] = u1.z; un[kk][7] = u1.w;
        }
        const int t0 = ck * CHUNK + w * 16;
        f16x8 af[4];
        const f16* qp = qkvo + ((size_t)b * S_LEN + t0 + (l & 15)) * NCOL + QOFF + h * 128 + (l >> 4) * 8;
#pragma unroll
        for (int kk = 0; kk < 4; kk++) af[kk] = *reinterpret_cast<const f16x8*>(qp + kk * 32);
        f16x8 cf[4], cfn[4];
#pragma unroll
        for (int kk = 0; kk < 4; kk++)
#pragma unroll
            for (int j = 0; j < 8; j++) { cf[kk][j] = (f16)c[kk][j]; cfn[kk][j] = (f16)nn[kk][j]; }
        f32x4 H  = (f32x4){0.f, 0.f, 0.f, 0.f};
        f32x4 Hn = (f32x4){0.f, 0.f, 0.f, 0.f};
#pragma unroll
        for (int kk = 0; kk < 4; kk++) {
            H  = __builtin_amdgcn_mfma_f32_16x16x32_f16(af[kk], cf[kk],  H,  0, 0, 0);
            Hn = __builtin_amdgcn_mfma_f32_16x16x32_f16(af[kk], cfn[kk], Hn, 0, 0, 0);
        }
        const int tt = t0 + (l >> 4) * 4;
        f16x4 hi = *reinterpret_cast<const f16x4*>(&hintraT[((size_t)bh * 256 + dv) * S_LEN + tt]);
        const float4 qnI = *reinterpret_cast<const float4*>(&qn_intra[(size_t)bh * S_LEN + tt]);
        const float qni[4] = {qnI.x, qnI.y, qnI.z, qnI.w};
#pragma unroll
        for (int i = 0; i < 4; i++) {
            const float4 g = gs4[(size_t)bh * S_LEN + tt + i];
            const float al = g.z;
            const float qn = qni[i] + al * Hn[i];
            const float rd = 1.f / (fmaxf(fabsf(qn), g.w) + 1e-6f);
            const float hval = ((float)hi[i] + al * H[i]) * rd;
            hbuf[((size_t)b * S_LEN + tt + i) * D_MODEL + h * 256 + dv] = (f16)hval;
        }
        const float F = gchunk[bh * NCHUNK + ck].x;
#pragma unroll
        for (int kk = 0; kk < 4; kk++)
#pragma unroll
            for (int j = 0; j < 8; j++) {
                c[kk][j]  = fmaf(F, c[kk][j],  (float)uf[kk][j]);
                nn[kk][j] = fmaf(F, nn[kk][j], un[kk][j]);
            }
    }
    if (w == 0) {
#pragma unroll
        for (int kk = 0; kk < 4; kk++)
#pragma unroll
            for (int j = 0; j < 8; j++) {
                const int dq = kk * 32 + (l >> 4) * 8 + j;
                Cf[((size_t)bh * 128 + dq) * 256 + dv] = c[kk][j];
            }
        if (vt == 0 && (l & 15) == 0) {
#pragma unroll
            for (int kk = 0; kk < 4; kk++)
#pragma unroll
                for (int j = 0; j < 8; j++) {
                    const int dq = kk * 32 + (l >> 4) * 8 + j;
                    nf[(size_t)bh * 128 + dq] = nn[kk][j];
                }
        }
    }
}

// ---------------- per-head layernorm * gamma * sigmoid(og), f16 in/out ----------------
__global__ __launch_bounds__(256) void norm_kernel(const f16* __restrict__ hbuf,
                                                   const f16* __restrict__ qkvo,
                                                   const float* __restrict__ gamma,
                                                   f16* __restrict__ hout) {
    const int row = blockIdx.x;
    const int tid = threadIdx.x;
    const int g = tid >> 5;
    const int l = tid & 31;
    const f16* hrow = hbuf + (size_t)row * D_MODEL + g * 256 + l * 8;
    f16x8 hv8 = *reinterpret_cast<const f16x8*>(hrow);
    float hv[8];
#pragma unroll
    for (int e = 0; e < 8; e++) hv[e] = (float)hv8[e];
    float s = 0.f, s2 = 0.f;
#pragma unroll
    for (int e = 0; e < 8; e++) { s += hv[e]; s2 += hv[e] * hv[e]; }
#pragma unroll
    for (int off = 1; off < 32; off <<= 1) {
        s  += __shfl_xor(s, off);
        s2 += __shfl_xor(s2, off);
    }
    const float mu  = s * (1.f / 256.f);
    const float var = s2 * (1.f / 256.f) - mu * mu;
    const float rs  = rsqrtf(var + 1e-6f);
    const f16* ogr = qkvo + (size_t)row * NCOL + OGOFF + g * 256 + l * 8;
    f16x8 og8 = *reinterpret_cast<const f16x8*>(ogr);
    const float* gam = gamma + g * 256 + l * 8;
    f16x8 o;
#pragma unroll
    for (int e = 0; e < 8; e++) {
        const float og  = (float)og8[e];
        const float sig = __builtin_amdgcn_rcpf(1.f + __expf(-og));
        const float hn  = (hv[e] - mu) * rs * gam[e];
        o[e] = (f16)(sig * hn);
    }
    *reinterpret_cast<f16x8*>(&hout[(size_t)row * D_MODEL + g * 256 + l * 8]) = o;
}

// ---------------- launch ----------------
extern "C" void kernel_launch(void* const* d_in, const int* in_sizes, int n_in,
                              void* d_out, int out_size, void* d_ws, size_t ws_size,
                              hipStream_t stream) {
    (void)in_sizes; (void)n_in; (void)out_size; (void)ws_size;
    const float* x     = (const float*)d_in[0];
    const float* Wq    = (const float*)d_in[1];
    const float* Wk    = (const float*)d_in[2];
    const float* Wv    = (const float*)d_in[3];
    const float* Wog   = (const float*)d_in[4];
    const float* Wig   = (const float*)d_in[5];
    const float* big   = (const float*)d_in[6];
    const float* Wfg   = (const float*)d_in[7];
    const float* bfg   = (const float*)d_in[8];
    const float* gamma = (const float*)d_in[9];
    const float* Wout  = (const float*)d_in[10];

    char* ws = (char*)d_ws;
    size_t off = 0;
    f16*    xf     = (f16*)(ws + off);    off += (size_t)NROWS * D_MODEL * 2;
    f16*    wcat   = (f16*)(ws + off);    off += (size_t)NCOL * D_MODEL * 2;
    f16*    woutf  = (f16*)(ws + off);    off += (size_t)D_MODEL * D_MODEL * 2;
    f16*    qkvo   = (f16*)(ws + off);    off += (size_t)NROWS * NCOL * 2;
    float4* gs4    = (float4*)(ws + off); off += (size_t)16 * S_LEN * 16;
    float2* gchunk = (float2*)(ws + off); off += (size_t)16 * NCHUNK * 8;
    float*  qn_i   = (float*)(ws + off);  off += (size_t)16 * S_LEN * 4;
    float*  UnB    = (float*)(ws + off);  off += (size_t)16 * NCHUNK * 128 * 4;
    f16*    Ubuf   = (f16*)(ws + off);    off += (size_t)16 * NCHUNK * 256 * 128 * 2;
    f16*    hinT   = (f16*)(ws + off);    off += (size_t)16 * 256 * S_LEN * 2;
    f16*    hbuf   = (f16*)(ws + off);    off += (size_t)NROWS * D_MODEL * 2;
    f16*    houtf  = xf;  // xf dead after GEMM1

    float* y  = (float*)d_out;
    float* Cf = y + (size_t)NROWS * D_MODEL;
    float* nf = Cf + (size_t)16 * 128 * 256;
    float* mf = nf + (size_t)16 * 128;

    // fused casts (x + all weights incl. Wig/Wfg into wcat rows 6144..6159)
    cast_all<<<24608, 256, 0, stream>>>(x, Wq, Wk, Wv, Wog, Wig, Wfg, Wout, xf, wcat, woutf);

    // fused qkvo+gates projection (f16 out); q columns pre-scaled by DQ^-0.5
    gemm_f16<f16><<<dim3(NCOL / 128, NROWS / 128), 256, 0, stream>>>(
        xf, wcat, qkvo, NROWS, NCOL, D_MODEL, NCOL, 1024, 0.08838834764831845f);

    // gate chunk decomposition (reads fused preacts)
    gate_scan<<<16, 64, 0, stream>>>(qkvo, big, bfg, gs4, gchunk, mf);

    // chunkwise mLSTM
    phaseA<<<512, 256, 0, stream>>>(qkvo, gs4, qn_i, Ubuf, hinT, UnB);
    phaseB<<<256, 256, 0, stream>>>(qkvo, Ubuf, hinT, gs4, gchunk, qn_i, UnB, hbuf, Cf, nf);

    // multihead norm + output gate
    norm_kernel<<<NROWS, 256, 0, stream>>>(hbuf, qkvo, gamma, houtf);

    // y = h_out @ Wout^T
    gemm_f16<float><<<dim3(D_MODEL / 128, NROWS / 128), 256, 0, stream>>>(
        houtf, woutf, y, NROWS, D_MODEL, D_MODEL, D_MODEL, 0, 1.f);
}

// Round 7
// 410.306 us; speedup vs baseline: 1.0697x; 1.0482x over previous
//
#include <hip/hip_runtime.h>

typedef _Float16 f16;
typedef f16 f16x8 __attribute__((ext_vector_type(8)));
typedef f16 f16x4 __attribute__((ext_vector_type(4)));
typedef float f32x4 __attribute__((ext_vector_type(4)));

#define S_LEN 2048
#define D_MODEL 2048
#define NHEADS 8
#define DQ 128
#define DV 256
#define NCOL 6272   // q(1024) | k(1024) | v(2048) | og(2048) | ig(8)@6144 | fg(8)@6152 | pad->6272
#define QOFF 0
#define KOFF 1024
#define VOFF 2048
#define OGOFF 4096
#define IGOFF 6144
#define NROWS 4096  // B*S
#define CHUNK 64
#define NCHUNK 32   // per sequence

// ---------------- fused f32 -> f16 casts (x + all weights incl. gates) ----------------
__global__ __launch_bounds__(256) void cast_all(const float* __restrict__ x,
                                                const float* __restrict__ Wq,
                                                const float* __restrict__ Wk,
                                                const float* __restrict__ Wv,
                                                const float* __restrict__ Wog,
                                                const float* __restrict__ Wig,
                                                const float* __restrict__ Wfg,
                                                const float* __restrict__ Wout,
                                                f16* __restrict__ xf,
                                                f16* __restrict__ wcat,
                                                f16* __restrict__ woutf) {
    int i = blockIdx.x * 256 + threadIdx.x;   // float4 index
    const float* src;
    f16* dst;
    int local;
    if (i < 2097152)      { src = x;    dst = xf;                         local = i; }
    else if (i < 2621440) { src = Wq;   dst = wcat;                       local = i - 2097152; }
    else if (i < 3145728) { src = Wk;   dst = wcat + (size_t)2097152;     local = i - 2621440; }
    else if (i < 4194304) { src = Wv;   dst = wcat + (size_t)4194304;     local = i - 3145728; }
    else if (i < 5242880) { src = Wog;  dst = wcat + (size_t)8388608;     local = i - 4194304; }
    else if (i < 5246976) { src = Wig;  dst = wcat + (size_t)12582912;    local = i - 5242880; }
    else if (i < 5251072) { src = Wfg;  dst = wcat + (size_t)12599296;    local = i - 5246976; }
    else                  { src = Wout; dst = woutf;                      local = i - 5251072; }
    float4 v = reinterpret_cast<const float4*>(src)[local];
    f16x4 o = { (f16)v.x, (f16)v.y, (f16)v.z, (f16)v.w };
    reinterpret_cast<f16x4*>(dst)[local] = o;
}

// ---------------- GEMM: C[M,N] = A[M,K] @ B[N,K]^T  (f16 in, OT out) ----------------
// m97 structure: 128x128 tile, BK=32, 4 waves, gload_lds staging, 2 barriers/K-step.
#define BK 32
template <typename OT>
__global__ __launch_bounds__(256) void gemm_f16(const f16* __restrict__ A,
                                                const f16* __restrict__ B,
                                                OT* __restrict__ C,
                                                int M, int N, int K, int ldc,
                                                int scale_cols, float scale) {
    __shared__ f16 As[128 * BK];   // 8 KB
    __shared__ f16 Bs[128 * BK];   // 8 KB
    const int tid  = threadIdx.x;
    const int lane = tid & 63;
    const int w    = tid >> 6;
    const int wr   = w >> 1, wc = w & 1;
    const int m0   = blockIdx.y * 128, n0 = blockIdx.x * 128;
    const int r16  = lane & 15;
    const int kg   = (lane >> 4) * 8;

    const int srow = tid >> 2;
    const int scol = (tid & 3) * 8;
    const f16* Ag = A + (size_t)(m0 + srow) * K + scol;
    const f16* Bg = B + (size_t)(n0 + srow) * K + scol;
    f16* As0 = &As[w * 512];
    f16* Bs0 = &Bs[w * 512];

    f32x4 acc[4][4];
#pragma unroll
    for (int i = 0; i < 4; i++)
#pragma unroll
        for (int j = 0; j < 4; j++) acc[i][j] = (f32x4){0.f, 0.f, 0.f, 0.f};

    for (int k0 = 0; k0 < K; k0 += BK) {
        __syncthreads();
        __builtin_amdgcn_global_load_lds(
            (const __attribute__((address_space(1))) void*)(Ag + k0),
            (__attribute__((address_space(3))) void*)(As0), 16, 0, 0);
        __builtin_amdgcn_global_load_lds(
            (const __attribute__((address_space(1))) void*)(Ag + (size_t)64 * K + k0),
            (__attribute__((address_space(3))) void*)(As0 + 2048), 16, 0, 0);
        __builtin_amdgcn_global_load_lds(
            (const __attribute__((address_space(1))) void*)(Bg + k0),
            (__attribute__((address_space(3))) void*)(Bs0), 16, 0, 0);
        __builtin_amdgcn_global_load_lds(
            (const __attribute__((address_space(1))) void*)(Bg + (size_t)64 * K + k0),
            (__attribute__((address_space(3))) void*)(Bs0 + 2048), 16, 0, 0);
        __syncthreads();

        f16x8 a[4], b[4];
#pragma unroll
        for (int i = 0; i < 4; i++)
            a[i] = *reinterpret_cast<const f16x8*>(&As[(wr * 64 + i * 16 + r16) * BK + kg]);
#pragma unroll
        for (int j = 0; j < 4; j++)
            b[j] = *reinterpret_cast<const f16x8*>(&Bs[(wc * 64 + j * 16 + r16) * BK + kg]);
#pragma unroll
        for (int i = 0; i < 4; i++)
#pragma unroll
            for (int j = 0; j < 4; j++)
                acc[i][j] = __builtin_amdgcn_mfma_f32_16x16x32_f16(a[i], b[j], acc[i][j], 0, 0, 0);
    }

    const int crow = m0 + wr * 64 + (lane >> 4) * 4;
    const int ccol = n0 + wc * 64 + r16;
#pragma unroll
    for (int i = 0; i < 4; i++) {
#pragma unroll
        for (int j = 0; j < 4; j++) {
            const int col = ccol + j * 16;
            const float sc = (col < scale_cols) ? scale : 1.f;
#pragma unroll
            for (int r = 0; r < 4; r++) {
                C[(size_t)(crow + i * 16 + r) * ldc + col] = (OT)(acc[i][j][r] * sc);
            }
        }
    }
}

// ---------------- gate scan: parallel transcendental pass + per-chunk scans ----------------
// gs4[bh][t] = (u_t, A_t, alpha_t, exp(-m_t)); gchunk[bh][j] = (F_j, G_j)
__global__ __launch_bounds__(256) void gate_scan(const f16* __restrict__ qkvo,
                                                 const float* __restrict__ big,
                                                 const float* __restrict__ bfg,
                                                 float4* __restrict__ gs4,
                                                 float2* __restrict__ gchunk,
                                                 float* __restrict__ mf) {
    const int bh = blockIdx.x;
    const int b = bh >> 3, h = bh & 7;
    const int tid = threadIdx.x;
    __shared__ float2 sif[S_LEN];   // (i_capped, f_log) per step, 16 KB
    __shared__ float2 comp[NCHUNK];
    const float bi = big[h], bff = bfg[h];
    // pass 1 (parallel over steps): soft-cap + log-sigmoid
    for (int t = tid; t < S_LEN; t += 256) {
        const f16* gp = qkvo + ((size_t)b * S_LEN + t) * NCOL + IGOFF;
        const float ip = (float)gp[h] + bi;
        const float fp = (float)gp[8 + h] + bff;
        const float ic = 15.f * tanhf(ip * (1.f / 15.f));
        const float fc = 15.f * tanhf(fp * (1.f / 15.f));
        const float flog = fminf(fc, 0.f) - log1pf(expf(-fabsf(fc)));
        sif[t] = make_float2(ic, flog);
    }
    __syncthreads();
    // pass 2 (one thread per chunk): chunk compositions
    if (tid < NCHUNK) {
        float bsum = 0.f, r = -1e30f;
        for (int s = 0; s < CHUNK; s++) {
            const float2 g = sif[tid * CHUNK + s];
            bsum += g.y;
            r = fmaxf(r, g.x - bsum);
        }
        comp[tid] = make_float2(bsum, r);
    }
    __syncthreads();
    // pass 3: chunk-start m + per-step outputs
    if (tid < NCHUNK) {
        float m0 = 0.f;   // m at chunk start (initial state m = 0)
        for (int c = 0; c < tid; c++) m0 = comp[c].x + fmaxf(m0, comp[c].y);
        float4* out = gs4 + (size_t)bh * S_LEN + tid * CHUNK;
        float bsum = 0.f, r = -1e30f;
        float mlast = 0.f, Alast = 0.f, alast = 0.f;
        for (int s = 0; s < CHUNK; s++) {
            const float2 g = sif[tid * CHUNK + s];
            bsum += g.y;
            const float uu = g.x - bsum;
            r = fmaxf(r, uu);
            const float mx = fmaxf(m0, r);
            const float mt = bsum + mx;
            const float At = -mx;
            const float al = expf(m0 + At);
            out[s] = make_float4(uu, At, al, expf(-mt));
            if (s == CHUNK - 1) { mlast = mt; Alast = At; alast = al; }
        }
        gchunk[bh * NCHUNK + tid] = make_float2(alast, Alast);
        if (tid == NCHUNK - 1) mf[bh] = mlast;
    }
}

// ---------------- phase A: per (bh, chunk) intra attention + chunk summaries ----------------
// LDS 74 KB -> 2 blocks/CU. Pl aliases Kn (Kn dead after S^T A-frags; barrier guards WAR).
__global__ __launch_bounds__(256) void phaseA(const f16* __restrict__ qkvo,
                                              const float4* __restrict__ gs4,
                                              float* __restrict__ qn_intra,
                                              f16* __restrict__ Ubuf,
                                              f16* __restrict__ hintraT,
                                              float* __restrict__ UnB) {
    __shared__ f16 Kn[64][136];     // K natural [s][dq] (+8 pad); tail-reused as Pl[64][72]
    __shared__ f16 KgT[128][72];    // gamma-scaled K^T [dq][s]
    __shared__ f16 VT[256][72];     // V^T [v][s]
    __shared__ float u_s[64], A_t[64];
    __shared__ float qnp[4][64];
    f16 (*Pl)[72] = reinterpret_cast<f16(*)[72]>(&Kn[0][0]);   // 64*72 <= 64*136

    const int bid = blockIdx.x;
    const int bh = bid >> 5, ck = bid & 31;
    const int b = bh >> 3, h = bh & 7;
    const int tid = threadIdx.x;
    const int w = tid >> 6, l = tid & 63;

    const size_t rowbase = (size_t)b * S_LEN + ck * CHUNK;

    if (tid < 64) {
        float4 g = gs4[(size_t)bh * S_LEN + ck * CHUNK + tid];
        u_s[tid] = g.x; A_t[tid] = g.y;
    }
    const int sK = tid & 63, quad = tid >> 6;
    // stage K natural (keep regs for KgT)
    f16x8 kreg[4];
    {
        const f16* kp = qkvo + (rowbase + sK) * NCOL + KOFF + h * 128 + quad * 32;
#pragma unroll
        for (int i = 0; i < 4; i++) kreg[i] = *reinterpret_cast<const f16x8*>(kp + i * 8);
#pragma unroll
        for (int i = 0; i < 4; i++) *reinterpret_cast<f16x8*>(&Kn[sK][quad * 32 + i * 8]) = kreg[i];
    }
    // stage V^T (scalar transpose; conflict-free: lanes write consecutive sK)
    {
        const f16* vp = qkvo + (rowbase + sK) * NCOL + VOFF + h * 256 + quad * 64;
#pragma unroll
        for (int i = 0; i < 8; i++) {
            f16x8 v = *reinterpret_cast<const f16x8*>(vp + i * 8);
#pragma unroll
            for (int e = 0; e < 8; e++) VT[quad * 64 + i * 8 + e][sK] = v[e];
        }
    }
    __syncthreads();
    // gamma-scaled K^T (gamma_s = exp(u_s + G), G = A_t[63])
    {
        const float gam = __expf(u_s[sK] + A_t[63]);
#pragma unroll
        for (int i = 0; i < 4; i++)
#pragma unroll
            for (int e = 0; e < 8; e++)
                KgT[quad * 32 + i * 8 + e][sK] = (f16)(gam * (float)kreg[i][e]);
    }
    // S^T mfma: A = Kn rows (wave's s-tile), B = Q from global
    f16x8 af[4];
#pragma unroll
    for (int kk = 0; kk < 4; kk++)
        af[kk] = *reinterpret_cast<const f16x8*>(&Kn[w * 16 + (l & 15)][kk * 32 + (l >> 4) * 8]);
    f32x4 st[4];
#pragma unroll
    for (int ct = 0; ct < 4; ct++) {
        st[ct] = (f32x4){0.f, 0.f, 0.f, 0.f};
#pragma unroll
        for (int kk = 0; kk < 4; kk++) {
            const f16* qp = qkvo + (rowbase + ct * 16 + (l & 15)) * NCOL + QOFF + h * 128 + kk * 32 + (l >> 4) * 8;
            f16x8 bf = *reinterpret_cast<const f16x8*>(qp);
            st[ct] = __builtin_amdgcn_mfma_f32_16x16x32_f16(af[kk], bf, st[ct], 0, 0, 0);
        }
    }
    __syncthreads();   // all waves done reading Kn -> safe to overwrite via Pl alias
    // P^T: weights + mask; qn partials; write P (natural [t][s]) into Pl (aliases Kn)
#pragma unroll
    for (int ct = 0; ct < 4; ct++) {
        const int tloc = ct * 16 + (l & 15);
        const float At = A_t[tloc];
        float part = 0.f;
        f16x4 pk;
#pragma unroll
        for (int i = 0; i < 4; i++) {
            const int sloc = w * 16 + (l >> 4) * 4 + i;
            const float val = (sloc <= tloc) ? st[ct][i] * __expf(At + u_s[sloc]) : 0.f;
            part += val;
            pk[i] = (f16)val;
        }
        part += __shfl_xor(part, 16);
        part += __shfl_xor(part, 32);
        if ((l >> 4) == 0) qnp[w][tloc] = part;
        *reinterpret_cast<f16x4*>(&Pl[tloc][w * 16 + (l >> 4) * 4]) = pk;
    }
    __syncthreads();
    if (tid < 64)
        qn_intra[(size_t)bh * S_LEN + ck * CHUNK + tid] =
            qnp[0][tid] + qnp[1][tid] + qnp[2][tid] + qnp[3][tid];
    // PV: h_intra(64x256), wave w -> t-tile w
    {
        f16x8 pa[2];
#pragma unroll
        for (int kk = 0; kk < 2; kk++)
            pa[kk] = *reinterpret_cast<const f16x8*>(&Pl[w * 16 + (l & 15)][kk * 32 + (l >> 4) * 8]);
#pragma unroll
        for (int vt = 0; vt < 16; vt++) {
            f32x4 acc = (f32x4){0.f, 0.f, 0.f, 0.f};
#pragma unroll
            for (int kk = 0; kk < 2; kk++) {
                f16x8 vb = *reinterpret_cast<const f16x8*>(&VT[vt * 16 + (l & 15)][kk * 32 + (l >> 4) * 8]);
                acc = __builtin_amdgcn_mfma_f32_16x16x32_f16(pa[kk], vb, acc, 0, 0, 0);
            }
            f16x4 hk;
#pragma unroll
            for (int i = 0; i < 4; i++) hk[i] = (f16)acc[i];
            const size_t addr = ((size_t)bh * 256 + vt * 16 + (l & 15)) * S_LEN
                              + ck * CHUNK + w * 16 + (l >> 4) * 4;
            *reinterpret_cast<f16x4*>(&hintraT[addr]) = hk;
        }
    }
    // U (chunk summary, stored [dv][dq]); wave w -> dv-tiles w*4..w*4+3
#pragma unroll
    for (int q = 0; q < 4; q++) {
        const int dvt = w * 4 + q;
        f16x8 vb[2];
#pragma unroll
        for (int kk = 0; kk < 2; kk++)
            vb[kk] = *reinterpret_cast<const f16x8*>(&VT[dvt * 16 + (l & 15)][kk * 32 + (l >> 4) * 8]);
#pragma unroll
        for (int dqt = 0; dqt < 8; dqt++) {
            f32x4 acc = (f32x4){0.f, 0.f, 0.f, 0.f};
#pragma unroll
            for (int kk = 0; kk < 2; kk++) {
                f16x8 ka = *reinterpret_cast<const f16x8*>(&KgT[dqt * 16 + (l & 15)][kk * 32 + (l >> 4) * 8]);
                acc = __builtin_amdgcn_mfma_f32_16x16x32_f16(ka, vb[kk], acc, 0, 0, 0);
            }
            f16x4 uk;
#pragma unroll
            for (int i = 0; i < 4; i++) uk[i] = (f16)acc[i];
            const size_t addr = (((size_t)bh * NCHUNK + ck) * 256 + dvt * 16 + (l & 15)) * 128
                              + dqt * 16 + (l >> 4) * 4;
            *reinterpret_cast<f16x4*>(&Ubuf[addr]) = uk;
        }
    }
    // Un row-sums: Un[dq] = sum_s KgT[dq][s]  (f32)
    {
        const int dq = tid >> 1, half = tid & 1;
        float sum = 0.f;
#pragma unroll
        for (int i = 0; i < 4; i++) {
            f16x8 kv = *reinterpret_cast<const f16x8*>(&KgT[dq][half * 32 + i * 8]);
#pragma unroll
            for (int e = 0; e < 8; e++) sum += (float)kv[e];
        }
        sum += __shfl_xor(sum, 1);
        if (half == 0) UnB[((size_t)bh * NCHUNK + ck) * 128 + dq] = sum;
    }
}

// ---------------- phase B: inter-chunk C and n recurrences + output ----------------
__global__ __launch_bounds__(256) void phaseB(const f16* __restrict__ qkvo,
                                              const f16* __restrict__ Ubuf,
                                              const f16* __restrict__ hintraT,
                                              const float4* __restrict__ gs4,
                                              const float2* __restrict__ gchunk,
                                              const float* __restrict__ qn_intra,
                                              const float* __restrict__ UnB,
                                              f16* __restrict__ hbuf,
                                              float* __restrict__ Cf,
                                              float* __restrict__ nf) {
    const int bid = blockIdx.x;
    const int bh = bid >> 4, vt = bid & 15;
    const int b = bh >> 3, h = bh & 7;
    const int tid = threadIdx.x, w = tid >> 6, l = tid & 63;
    const int dv = vt * 16 + (l & 15);

    float c[4][8];
    float nn[4][8];
#pragma unroll
    for (int kk = 0; kk < 4; kk++)
#pragma unroll
        for (int j = 0; j < 8; j++) { c[kk][j] = 0.f; nn[kk][j] = 0.f; }

    for (int ck = 0; ck < NCHUNK; ck++) {
        f16x8 uf[4];
        const f16* ub = Ubuf + (((size_t)bh * NCHUNK + ck) * 256 + dv) * 128 + (l >> 4) * 8;
#pragma unroll
        for (int kk = 0; kk < 4; kk++) uf[kk] = *reinterpret_cast<const f16x8*>(ub + kk * 32);
        float un[4][8];
        const float* unp = UnB + ((size_t)bh * NCHUNK + ck) * 128 + (l >> 4) * 8;
#pragma unroll
        for (int kk = 0; kk < 4; kk++) {
            const float4 u0 = *reinterpret_cast<const float4*>(unp + kk * 32);
            const float4 u1 = *reinterpret_cast<const float4*>(unp + kk * 32 + 4);
            un[kk][0] = u0.x; un[kk][1] = u0.y; un[kk][2] = u0.z; un[kk][3] = u0.w;
            un[kk][4] = u1.x; un[kk][5] = u1.y; un[kk][6] = u1.z; un[kk][7] = u1.w;
        }
        const int t0 = ck * CHUNK + w * 16;
        f16x8 af[4];
        const f16* qp = qkvo + ((size_t)b * S_LEN + t0 + (l & 15)) * NCOL + QOFF + h * 128 + (l >> 4) * 8;
#pragma unroll
        for (int kk = 0; kk < 4; kk++) af[kk] = *reinterpret_cast<const f16x8*>(qp + kk * 32);
        f16x8 cf[4], cfn[4];
#pragma unroll
        for (int kk = 0; kk < 4; kk++)
#pragma unroll
            for (int j = 0; j < 8; j++) { cf[kk][j] = (f16)c[kk][j]; cfn[kk][j] = (f16)nn[kk][j]; }
        f32x4 H  = (f32x4){0.f, 0.f, 0.f, 0.f};
        f32x4 Hn = (f32x4){0.f, 0.f, 0.f, 0.f};
#pragma unroll
        for (int kk = 0; kk < 4; kk++) {
            H  = __builtin_amdgcn_mfma_f32_16x16x32_f16(af[kk], cf[kk],  H,  0, 0, 0);
            Hn = __builtin_amdgcn_mfma_f32_16x16x32_f16(af[kk], cfn[kk], Hn, 0, 0, 0);
        }
        const int tt = t0 + (l >> 4) * 4;
        f16x4 hi = *reinterpret_cast<const f16x4*>(&hintraT[((size_t)bh * 256 + dv) * S_LEN + tt]);
        const float4 qnI = *reinterpret_cast<const float4*>(&qn_intra[(size_t)bh * S_LEN + tt]);
        const float qni[4] = {qnI.x, qnI.y, qnI.z, qnI.w};
#pragma unroll
        for (int i = 0; i < 4; i++) {
            const float4 g = gs4[(size_t)bh * S_LEN + tt + i];
            const float al = g.z;
            const float qn = qni[i] + al * Hn[i];
            const float rd = 1.f / (fmaxf(fabsf(qn), g.w) + 1e-6f);
            const float hval = ((float)hi[i] + al * H[i]) * rd;
            hbuf[((size_t)b * S_LEN + tt + i) * D_MODEL + h * 256 + dv] = (f16)hval;
        }
        const float F = gchunk[bh * NCHUNK + ck].x;
#pragma unroll
        for (int kk = 0; kk < 4; kk++)
#pragma unroll
            for (int j = 0; j < 8; j++) {
                c[kk][j]  = fmaf(F, c[kk][j],  (float)uf[kk][j]);
                nn[kk][j] = fmaf(F, nn[kk][j], un[kk][j]);
            }
    }
    if (w == 0) {
#pragma unroll
        for (int kk = 0; kk < 4; kk++)
#pragma unroll
            for (int j = 0; j < 8; j++) {
                const int dq = kk * 32 + (l >> 4) * 8 + j;
                Cf[((size_t)bh * 128 + dq) * 256 + dv] = c[kk][j];
            }
        if (vt == 0 && (l & 15) == 0) {
#pragma unroll
            for (int kk = 0; kk < 4; kk++)
#pragma unroll
                for (int j = 0; j < 8; j++) {
                    const int dq = kk * 32 + (l >> 4) * 8 + j;
                    nf[(size_t)bh * 128 + dq] = nn[kk][j];
                }
        }
    }
}

// ---------------- per-head layernorm * gamma * sigmoid(og), f16 in/out ----------------
__global__ __launch_bounds__(256) void norm_kernel(const f16* __restrict__ hbuf,
                                                   const f16* __restrict__ qkvo,
                                                   const float* __restrict__ gamma,
                                                   f16* __restrict__ hout) {
    const int row = blockIdx.x;
    const int tid = threadIdx.x;
    const int g = tid >> 5;
    const int l = tid & 31;
    const f16* hrow = hbuf + (size_t)row * D_MODEL + g * 256 + l * 8;
    f16x8 hv8 = *reinterpret_cast<const f16x8*>(hrow);
    float hv[8];
#pragma unroll
    for (int e = 0; e < 8; e++) hv[e] = (float)hv8[e];
    float s = 0.f, s2 = 0.f;
#pragma unroll
    for (int e = 0; e < 8; e++) { s += hv[e]; s2 += hv[e] * hv[e]; }
#pragma unroll
    for (int off = 1; off < 32; off <<= 1) {
        s  += __shfl_xor(s, off);
        s2 += __shfl_xor(s2, off);
    }
    const float mu  = s * (1.f / 256.f);
    const float var = s2 * (1.f / 256.f) - mu * mu;
    const float rs  = rsqrtf(var + 1e-6f);
    const f16* ogr = qkvo + (size_t)row * NCOL + OGOFF + g * 256 + l * 8;
    f16x8 og8 = *reinterpret_cast<const f16x8*>(ogr);
    const float* gam = gamma + g * 256 + l * 8;
    f16x8 o;
#pragma unroll
    for (int e = 0; e < 8; e++) {
        const float og  = (float)og8[e];
        const float sig = __builtin_amdgcn_rcpf(1.f + __expf(-og));
        const float hn  = (hv[e] - mu) * rs * gam[e];
        o[e] = (f16)(sig * hn);
    }
    *reinterpret_cast<f16x8*>(&hout[(size_t)row * D_MODEL + g * 256 + l * 8]) = o;
}

// ---------------- launch ----------------
extern "C" void kernel_launch(void* const* d_in, const int* in_sizes, int n_in,
                              void* d_out, int out_size, void* d_ws, size_t ws_size,
                              hipStream_t stream) {
    (void)in_sizes; (void)n_in; (void)out_size; (void)ws_size;
    const float* x     = (const float*)d_in[0];
    const float* Wq    = (const float*)d_in[1];
    const float* Wk    = (const float*)d_in[2];
    const float* Wv    = (const float*)d_in[3];
    const float* Wog   = (const float*)d_in[4];
    const float* Wig   = (const float*)d_in[5];
    const float* big   = (const float*)d_in[6];
    const float* Wfg   = (const float*)d_in[7];
    const float* bfg   = (const float*)d_in[8];
    const float* gamma = (const float*)d_in[9];
    const float* Wout  = (const float*)d_in[10];

    char* ws = (char*)d_ws;
    size_t off = 0;
    f16*    xf     = (f16*)(ws + off);    off += (size_t)NROWS * D_MODEL * 2;
    f16*    wcat   = (f16*)(ws + off);    off += (size_t)NCOL * D_MODEL * 2;
    f16*    woutf  = (f16*)(ws + off);    off += (size_t)D_MODEL * D_MODEL * 2;
    f16*    qkvo   = (f16*)(ws + off);    off += (size_t)NROWS * NCOL * 2;
    float4* gs4    = (float4*)(ws + off); off += (size_t)16 * S_LEN * 16;
    float2* gchunk = (float2*)(ws + off); off += (size_t)16 * NCHUNK * 8;
    float*  qn_i   = (float*)(ws + off);  off += (size_t)16 * S_LEN * 4;
    float*  UnB    = (float*)(ws + off);  off += (size_t)16 * NCHUNK * 128 * 4;
    f16*    Ubuf   = (f16*)(ws + off);    off += (size_t)16 * NCHUNK * 256 * 128 * 2;
    f16*    hinT   = (f16*)(ws + off);    off += (size_t)16 * 256 * S_LEN * 2;
    f16*    hbuf   = (f16*)(ws + off);    off += (size_t)NROWS * D_MODEL * 2;
    f16*    houtf  = xf;  // xf dead after GEMM1

    float* y  = (float*)d_out;
    float* Cf = y + (size_t)NROWS * D_MODEL;
    float* nf = Cf + (size_t)16 * 128 * 256;
    float* mf = nf + (size_t)16 * 128;

    // fused casts (x + all weights incl. Wig/Wfg into wcat rows 6144..6159)
    cast_all<<<24608, 256, 0, stream>>>(x, Wq, Wk, Wv, Wog, Wig, Wfg, Wout, xf, wcat, woutf);

    // fused qkvo+gates projection (f16 out); q columns pre-scaled by DQ^-0.5
    gemm_f16<f16><<<dim3(NCOL / 128, NROWS / 128), 256, 0, stream>>>(
        xf, wcat, qkvo, NROWS, NCOL, D_MODEL, NCOL, 1024, 0.08838834764831845f);

    // gate chunk decomposition (reads fused preacts)
    gate_scan<<<16, 256, 0, stream>>>(qkvo, big, bfg, gs4, gchunk, mf);

    // chunkwise mLSTM
    phaseA<<<512, 256, 0, stream>>>(qkvo, gs4, qn_i, Ubuf, hinT, UnB);
    phaseB<<<256, 256, 0, stream>>>(qkvo, Ubuf, hinT, gs4, gchunk, qn_i, UnB, hbuf, Cf, nf);

    // multihead norm + output gate
    norm_kernel<<<NROWS, 256, 0, stream>>>(hbuf, qkvo, gamma, houtf);

    // y = h_out @ Wout^T
    gemm_f16<float><<<dim3(D_MODEL / 128, NROWS / 128), 256, 0, stream>>>(
        houtf, woutf, y, NROWS, D_MODEL, D_MODEL, D_MODEL, 0, 1.f);
}

// Round 8
// 406.220 us; speedup vs baseline: 1.0805x; 1.0101x over previous
//
#include <hip/hip_runtime.h>

typedef _Float16 f16;
typedef f16 f16x8 __attribute__((ext_vector_type(8)));
typedef f16 f16x4 __attribute__((ext_vector_type(4)));
typedef float f32x4 __attribute__((ext_vector_type(4)));

#define S_LEN 2048
#define D_MODEL 2048
#define NHEADS 8
#define DQ 128
#define DV 256
#define NCOL 6272   // q(1024) | k(1024) | v(2048) | og(2048) | ig(8)@6144 | fg(8)@6152 | pad->6272
#define QOFF 0
#define KOFF 1024
#define VOFF 2048
#define OGOFF 4096
#define IGOFF 6144
#define NROWS 4096  // B*S
#define CHUNK 64
#define NCHUNK 32   // per sequence

// ---------------- fused f32 -> f16 casts (x + all weights incl. gates) ----------------
__global__ __launch_bounds__(256) void cast_all(const float* __restrict__ x,
                                                const float* __restrict__ Wq,
                                                const float* __restrict__ Wk,
                                                const float* __restrict__ Wv,
                                                const float* __restrict__ Wog,
                                                const float* __restrict__ Wig,
                                                const float* __restrict__ Wfg,
                                                const float* __restrict__ Wout,
                                                f16* __restrict__ xf,
                                                f16* __restrict__ wcat,
                                                f16* __restrict__ woutf) {
    int i = blockIdx.x * 256 + threadIdx.x;   // float4 index
    const float* src;
    f16* dst;
    int local;
    if (i < 2097152)      { src = x;    dst = xf;                         local = i; }
    else if (i < 2621440) { src = Wq;   dst = wcat;                       local = i - 2097152; }
    else if (i < 3145728) { src = Wk;   dst = wcat + (size_t)2097152;     local = i - 2621440; }
    else if (i < 4194304) { src = Wv;   dst = wcat + (size_t)4194304;     local = i - 3145728; }
    else if (i < 5242880) { src = Wog;  dst = wcat + (size_t)8388608;     local = i - 4194304; }
    else if (i < 5246976) { src = Wig;  dst = wcat + (size_t)12582912;    local = i - 5242880; }
    else if (i < 5251072) { src = Wfg;  dst = wcat + (size_t)12599296;    local = i - 5246976; }
    else                  { src = Wout; dst = woutf;                      local = i - 5251072; }
    float4 v = reinterpret_cast<const float4*>(src)[local];
    f16x4 o = { (f16)v.x, (f16)v.y, (f16)v.z, (f16)v.w };
    reinterpret_cast<f16x4*>(dst)[local] = o;
}

// ---------------- GEMM: C[M,N] = A[M,K] @ B[N,K]^T  (f16 in, OT out) ----------------
// m97 structure: 128x128 tile, BK=32, 4 waves, gload_lds staging, 2 barriers/K-step.
// Launch with grid.x padded to a multiple of 8 so XCD = x%8 is y-invariant
// (fixed per-XCD B-panel set -> L2-resident B; the 48->49 regression was this).
#define BK 32
template <typename OT>
__global__ __launch_bounds__(256) void gemm_f16(const f16* __restrict__ A,
                                                const f16* __restrict__ B,
                                                OT* __restrict__ C,
                                                int M, int N, int K, int ldc,
                                                int scale_cols, float scale) {
    const int m0 = blockIdx.y * 128, n0 = blockIdx.x * 128;
    if (n0 >= N) return;   // padding blocks retire immediately

    __shared__ f16 As[128 * BK];   // 8 KB
    __shared__ f16 Bs[128 * BK];   // 8 KB
    const int tid  = threadIdx.x;
    const int lane = tid & 63;
    const int w    = tid >> 6;
    const int wr   = w >> 1, wc = w & 1;
    const int r16  = lane & 15;
    const int kg   = (lane >> 4) * 8;

    const int srow = tid >> 2;
    const int scol = (tid & 3) * 8;
    const f16* Ag = A + (size_t)(m0 + srow) * K + scol;
    const f16* Bg = B + (size_t)(n0 + srow) * K + scol;
    f16* As0 = &As[w * 512];
    f16* Bs0 = &Bs[w * 512];

    f32x4 acc[4][4];
#pragma unroll
    for (int i = 0; i < 4; i++)
#pragma unroll
        for (int j = 0; j < 4; j++) acc[i][j] = (f32x4){0.f, 0.f, 0.f, 0.f};

    for (int k0 = 0; k0 < K; k0 += BK) {
        __syncthreads();
        __builtin_amdgcn_global_load_lds(
            (const __attribute__((address_space(1))) void*)(Ag + k0),
            (__attribute__((address_space(3))) void*)(As0), 16, 0, 0);
        __builtin_amdgcn_global_load_lds(
            (const __attribute__((address_space(1))) void*)(Ag + (size_t)64 * K + k0),
            (__attribute__((address_space(3))) void*)(As0 + 2048), 16, 0, 0);
        __builtin_amdgcn_global_load_lds(
            (const __attribute__((address_space(1))) void*)(Bg + k0),
            (__attribute__((address_space(3))) void*)(Bs0), 16, 0, 0);
        __builtin_amdgcn_global_load_lds(
            (const __attribute__((address_space(1))) void*)(Bg + (size_t)64 * K + k0),
            (__attribute__((address_space(3))) void*)(Bs0 + 2048), 16, 0, 0);
        __syncthreads();

        f16x8 a[4], b[4];
#pragma unroll
        for (int i = 0; i < 4; i++)
            a[i] = *reinterpret_cast<const f16x8*>(&As[(wr * 64 + i * 16 + r16) * BK + kg]);
#pragma unroll
        for (int j = 0; j < 4; j++)
            b[j] = *reinterpret_cast<const f16x8*>(&Bs[(wc * 64 + j * 16 + r16) * BK + kg]);
#pragma unroll
        for (int i = 0; i < 4; i++)
#pragma unroll
            for (int j = 0; j < 4; j++)
                acc[i][j] = __builtin_amdgcn_mfma_f32_16x16x32_f16(a[i], b[j], acc[i][j], 0, 0, 0);
    }

    const int crow = m0 + wr * 64 + (lane >> 4) * 4;
    const int ccol = n0 + wc * 64 + r16;
#pragma unroll
    for (int i = 0; i < 4; i++) {
#pragma unroll
        for (int j = 0; j < 4; j++) {
            const int col = ccol + j * 16;
            const float sc = (col < scale_cols) ? scale : 1.f;
#pragma unroll
            for (int r = 0; r < 4; r++) {
                C[(size_t)(crow + i * 16 + r) * ldc + col] = (OT)(acc[i][j][r] * sc);
            }
        }
    }
}

// ---------------- gate scan: parallel transcendental pass + per-chunk scans ----------------
// gs4[bh][t] = (u_t, A_t, alpha_t, exp(-m_t)); gchunk[bh][j] = (F_j, G_j)
__global__ __launch_bounds__(256) void gate_scan(const f16* __restrict__ qkvo,
                                                 const float* __restrict__ big,
                                                 const float* __restrict__ bfg,
                                                 float4* __restrict__ gs4,
                                                 float2* __restrict__ gchunk,
                                                 float* __restrict__ mf) {
    const int bh = blockIdx.x;
    const int b = bh >> 3, h = bh & 7;
    const int tid = threadIdx.x;
    __shared__ float2 sif[S_LEN];   // (i_capped, f_log) per step, 16 KB
    __shared__ float2 comp[NCHUNK];
    const float bi = big[h], bff = bfg[h];
    // pass 1 (parallel over steps): soft-cap + log-sigmoid
    for (int t = tid; t < S_LEN; t += 256) {
        const f16* gp = qkvo + ((size_t)b * S_LEN + t) * NCOL + IGOFF;
        const float ip = (float)gp[h] + bi;
        const float fp = (float)gp[8 + h] + bff;
        const float ic = 15.f * tanhf(ip * (1.f / 15.f));
        const float fc = 15.f * tanhf(fp * (1.f / 15.f));
        const float flog = fminf(fc, 0.f) - log1pf(expf(-fabsf(fc)));
        sif[t] = make_float2(ic, flog);
    }
    __syncthreads();
    // pass 2 (one thread per chunk): chunk compositions
    if (tid < NCHUNK) {
        float bsum = 0.f, r = -1e30f;
        for (int s = 0; s < CHUNK; s++) {
            const float2 g = sif[tid * CHUNK + s];
            bsum += g.y;
            r = fmaxf(r, g.x - bsum);
        }
        comp[tid] = make_float2(bsum, r);
    }
    __syncthreads();
    // pass 3: chunk-start m + per-step outputs
    if (tid < NCHUNK) {
        float m0 = 0.f;   // m at chunk start (initial state m = 0)
        for (int c = 0; c < tid; c++) m0 = comp[c].x + fmaxf(m0, comp[c].y);
        float4* out = gs4 + (size_t)bh * S_LEN + tid * CHUNK;
        float bsum = 0.f, r = -1e30f;
        float mlast = 0.f, Alast = 0.f, alast = 0.f;
        for (int s = 0; s < CHUNK; s++) {
            const float2 g = sif[tid * CHUNK + s];
            bsum += g.y;
            const float uu = g.x - bsum;
            r = fmaxf(r, uu);
            const float mx = fmaxf(m0, r);
            const float mt = bsum + mx;
            const float At = -mx;
            const float al = expf(m0 + At);
            out[s] = make_float4(uu, At, al, expf(-mt));
            if (s == CHUNK - 1) { mlast = mt; Alast = At; alast = al; }
        }
        gchunk[bh * NCHUNK + tid] = make_float2(alast, Alast);
        if (tid == NCHUNK - 1) mf[bh] = mlast;
    }
}

// ---------------- phase A: per (bh, chunk) intra attention + chunk summaries ----------------
// LDS 74 KB -> 2 blocks/CU. Pl aliases Kn (Kn dead after S^T A-frags; barrier guards WAR).
__global__ __launch_bounds__(256) void phaseA(const f16* __restrict__ qkvo,
                                              const float4* __restrict__ gs4,
                                              float* __restrict__ qn_intra,
                                              f16* __restrict__ Ubuf,
                                              f16* __restrict__ hintraT,
                                              float* __restrict__ UnB) {
    __shared__ f16 Kn[64][136];     // K natural [s][dq] (+8 pad); tail-reused as Pl[64][72]
    __shared__ f16 KgT[128][72];    // gamma-scaled K^T [dq][s]
    __shared__ f16 VT[256][72];     // V^T [v][s]
    __shared__ float u_s[64], A_t[64];
    __shared__ float qnp[4][64];
    f16 (*Pl)[72] = reinterpret_cast<f16(*)[72]>(&Kn[0][0]);   // 64*72 <= 64*136

    const int bid = blockIdx.x;
    const int bh = bid >> 5, ck = bid & 31;
    const int b = bh >> 3, h = bh & 7;
    const int tid = threadIdx.x;
    const int w = tid >> 6, l = tid & 63;

    const size_t rowbase = (size_t)b * S_LEN + ck * CHUNK;

    if (tid < 64) {
        float4 g = gs4[(size_t)bh * S_LEN + ck * CHUNK + tid];
        u_s[tid] = g.x; A_t[tid] = g.y;
    }
    const int sK = tid & 63, quad = tid >> 6;
    // stage K natural (keep regs for KgT)
    f16x8 kreg[4];
    {
        const f16* kp = qkvo + (rowbase + sK) * NCOL + KOFF + h * 128 + quad * 32;
#pragma unroll
        for (int i = 0; i < 4; i++) kreg[i] = *reinterpret_cast<const f16x8*>(kp + i * 8);
#pragma unroll
        for (int i = 0; i < 4; i++) *reinterpret_cast<f16x8*>(&Kn[sK][quad * 32 + i * 8]) = kreg[i];
    }
    // stage V^T (scalar transpose; conflict-free: lanes write consecutive sK)
    {
        const f16* vp = qkvo + (rowbase + sK) * NCOL + VOFF + h * 256 + quad * 64;
#pragma unroll
        for (int i = 0; i < 8; i++) {
            f16x8 v = *reinterpret_cast<const f16x8*>(vp + i * 8);
#pragma unroll
            for (int e = 0; e < 8; e++) VT[quad * 64 + i * 8 + e][sK] = v[e];
        }
    }
    __syncthreads();
    // gamma-scaled K^T (gamma_s = exp(u_s + G), G = A_t[63])
    {
        const float gam = __expf(u_s[sK] + A_t[63]);
#pragma unroll
        for (int i = 0; i < 4; i++)
#pragma unroll
            for (int e = 0; e < 8; e++)
                KgT[quad * 32 + i * 8 + e][sK] = (f16)(gam * (float)kreg[i][e]);
    }
    // S^T mfma: A = Kn rows (wave's s-tile), B = Q from global
    f16x8 af[4];
#pragma unroll
    for (int kk = 0; kk < 4; kk++)
        af[kk] = *reinterpret_cast<const f16x8*>(&Kn[w * 16 + (l & 15)][kk * 32 + (l >> 4) * 8]);
    f32x4 st[4];
#pragma unroll
    for (int ct = 0; ct < 4; ct++) {
        st[ct] = (f32x4){0.f, 0.f, 0.f, 0.f};
#pragma unroll
        for (int kk = 0; kk < 4; kk++) {
            const f16* qp = qkvo + (rowbase + ct * 16 + (l & 15)) * NCOL + QOFF + h * 128 + kk * 32 + (l >> 4) * 8;
            f16x8 bf = *reinterpret_cast<const f16x8*>(qp);
            st[ct] = __builtin_amdgcn_mfma_f32_16x16x32_f16(af[kk], bf, st[ct], 0, 0, 0);
        }
    }
    __syncthreads();   // all waves done reading Kn -> safe to overwrite via Pl alias
    // P^T: weights + mask; qn partials; write P (natural [t][s]) into Pl (aliases Kn)
#pragma unroll
    for (int ct = 0; ct < 4; ct++) {
        const int tloc = ct * 16 + (l & 15);
        const float At = A_t[tloc];
        float part = 0.f;
        f16x4 pk;
#pragma unroll
        for (int i = 0; i < 4; i++) {
            const int sloc = w * 16 + (l >> 4) * 4 + i;
            const float val = (sloc <= tloc) ? st[ct][i] * __expf(At + u_s[sloc]) : 0.f;
            part += val;
            pk[i] = (f16)val;
        }
        part += __shfl_xor(part, 16);
        part += __shfl_xor(part, 32);
        if ((l >> 4) == 0) qnp[w][tloc] = part;
        *reinterpret_cast<f16x4*>(&Pl[tloc][w * 16 + (l >> 4) * 4]) = pk;
    }
    __syncthreads();
    if (tid < 64)
        qn_intra[(size_t)bh * S_LEN + ck * CHUNK + tid] =
            qnp[0][tid] + qnp[1][tid] + qnp[2][tid] + qnp[3][tid];
    // PV: h_intra(64x256), wave w -> t-tile w
    {
        f16x8 pa[2];
#pragma unroll
        for (int kk = 0; kk < 2; kk++)
            pa[kk] = *reinterpret_cast<const f16x8*>(&Pl[w * 16 + (l & 15)][kk * 32 + (l >> 4) * 8]);
#pragma unroll
        for (int vt = 0; vt < 16; vt++) {
            f32x4 acc = (f32x4){0.f, 0.f, 0.f, 0.f};
#pragma unroll
            for (int kk = 0; kk < 2; kk++) {
                f16x8 vb = *reinterpret_cast<const f16x8*>(&VT[vt * 16 + (l & 15)][kk * 32 + (l >> 4) * 8]);
                acc = __builtin_amdgcn_mfma_f32_16x16x32_f16(pa[kk], vb, acc, 0, 0, 0);
            }
            f16x4 hk;
#pragma unroll
            for (int i = 0; i < 4; i++) hk[i] = (f16)acc[i];
            const size_t addr = ((size_t)bh * 256 + vt * 16 + (l & 15)) * S_LEN
                              + ck * CHUNK + w * 16 + (l >> 4) * 4;
            *reinterpret_cast<f16x4*>(&hintraT[addr]) = hk;
        }
    }
    // U (chunk summary, stored [dv][dq]); wave w -> dv-tiles w*4..w*4+3
#pragma unroll
    for (int q = 0; q < 4; q++) {
        const int dvt = w * 4 + q;
        f16x8 vb[2];
#pragma unroll
        for (int kk = 0; kk < 2; kk++)
            vb[kk] = *reinterpret_cast<const f16x8*>(&VT[dvt * 16 + (l & 15)][kk * 32 + (l >> 4) * 8]);
#pragma unroll
        for (int dqt = 0; dqt < 8; dqt++) {
            f32x4 acc = (f32x4){0.f, 0.f, 0.f, 0.f};
#pragma unroll
            for (int kk = 0; kk < 2; kk++) {
                f16x8 ka = *reinterpret_cast<const f16x8*>(&KgT[dqt * 16 + (l & 15)][kk * 32 + (l >> 4) * 8]);
                acc = __builtin_amdgcn_mfma_f32_16x16x32_f16(ka, vb[kk], acc, 0, 0, 0);
            }
            f16x4 uk;
#pragma unroll
            for (int i = 0; i < 4; i++) uk[i] = (f16)acc[i];
            const size_t addr = (((size_t)bh * NCHUNK + ck) * 256 + dvt * 16 + (l & 15)) * 128
                              + dqt * 16 + (l >> 4) * 4;
            *reinterpret_cast<f16x4*>(&Ubuf[addr]) = uk;
        }
    }
    // Un row-sums: Un[dq] = sum_s KgT[dq][s]  (f32)
    {
        const int dq = tid >> 1, half = tid & 1;
        float sum = 0.f;
#pragma unroll
        for (int i = 0; i < 4; i++) {
            f16x8 kv = *reinterpret_cast<const f16x8*>(&KgT[dq][half * 32 + i * 8]);
#pragma unroll
            for (int e = 0; e < 8; e++) sum += (float)kv[e];
        }
        sum += __shfl_xor(sum, 1);
        if (half == 0) UnB[((size_t)bh * NCHUNK + ck) * 128 + dq] = sum;
    }
}

// ---------------- phase B: inter-chunk C and n recurrences + output ----------------
__global__ __launch_bounds__(256) void phaseB(const f16* __restrict__ qkvo,
                                              const f16* __restrict__ Ubuf,
                                              const f16* __restrict__ hintraT,
                                              const float4* __restrict__ gs4,
                                              const float2* __restrict__ gchunk,
                                              const float* __restrict__ qn_intra,
                                              const float* __restrict__ UnB,
                                              f16* __restrict__ hbuf,
                                              float* __restrict__ Cf,
                                              float* __restrict__ nf) {
    const int bid = blockIdx.x;
    const int bh = bid >> 4, vt = bid & 15;
    const int b = bh >> 3, h = bh & 7;
    const int tid = threadIdx.x, w = tid >> 6, l = tid & 63;
    const int dv = vt * 16 + (l & 15);

    float c[4][8];
    float nn[4][8];
#pragma unroll
    for (int kk = 0; kk < 4; kk++)
#pragma unroll
        for (int j = 0; j < 8; j++) { c[kk][j] = 0.f; nn[kk][j] = 0.f; }

    for (int ck = 0; ck < NCHUNK; ck++) {
        f16x8 uf[4];
        const f16* ub = Ubuf + (((size_t)bh * NCHUNK + ck) * 256 + dv) * 128 + (l >> 4) * 8;
#pragma unroll
        for (int kk = 0; kk < 4; kk++) uf[kk] = *reinterpret_cast<const f16x8*>(ub + kk * 32);
        float un[4][8];
        const float* unp = UnB + ((size_t)bh * NCHUNK + ck) * 128 + (l >> 4) * 8;
#pragma unroll
        for (int kk = 0; kk < 4; kk++) {
            const float4 u0 = *reinterpret_cast<const float4*>(unp + kk * 32);
            const float4 u1 = *reinterpret_cast<const float4*>(unp + kk * 32 + 4);
            un[kk][0] = u0.x; un[kk][1] = u0.y; un[kk][2] = u0.z; un[kk][3] = u0.w;
            un[kk][4] = u1.x; un[kk][5] = u1.y; un[kk][6] = u1.z; un[kk][7] = u1.w;
        }
        const int t0 = ck * CHUNK + w * 16;
        f16x8 af[4];
        const f16* qp = qkvo + ((size_t)b * S_LEN + t0 + (l & 15)) * NCOL + QOFF + h * 128 + (l >> 4) * 8;
#pragma unroll
        for (int kk = 0; kk < 4; kk++) af[kk] = *reinterpret_cast<const f16x8*>(qp + kk * 32);
        f16x8 cf[4], cfn[4];
#pragma unroll
        for (int kk = 0; kk < 4; kk++)
#pragma unroll
            for (int j = 0; j < 8; j++) { cf[kk][j] = (f16)c[kk][j]; cfn[kk][j] = (f16)nn[kk][j]; }
        f32x4 H  = (f32x4){0.f, 0.f, 0.f, 0.f};
        f32x4 Hn = (f32x4){0.f, 0.f, 0.f, 0.f};
#pragma unroll
        for (int kk = 0; kk < 4; kk++) {
            H  = __builtin_amdgcn_mfma_f32_16x16x32_f16(af[kk], cf[kk],  H,  0, 0, 0);
            Hn = __builtin_amdgcn_mfma_f32_16x16x32_f16(af[kk], cfn[kk], Hn, 0, 0, 0);
        }
        const int tt = t0 + (l >> 4) * 4;
        f16x4 hi = *reinterpret_cast<const f16x4*>(&hintraT[((size_t)bh * 256 + dv) * S_LEN + tt]);
        const float4 qnI = *reinterpret_cast<const float4*>(&qn_intra[(size_t)bh * S_LEN + tt]);
        const float qni[4] = {qnI.x, qnI.y, qnI.z, qnI.w};
#pragma unroll
        for (int i = 0; i < 4; i++) {
            const float4 g = gs4[(size_t)bh * S_LEN + tt + i];
            const float al = g.z;
            const float qn = qni[i] + al * Hn[i];
            const float rd = 1.f / (fmaxf(fabsf(qn), g.w) + 1e-6f);
            const float hval = ((float)hi[i] + al * H[i]) * rd;
            hbuf[((size_t)b * S_LEN + tt + i) * D_MODEL + h * 256 + dv] = (f16)hval;
        }
        const float F = gchunk[bh * NCHUNK + ck].x;
#pragma unroll
        for (int kk = 0; kk < 4; kk++)
#pragma unroll
            for (int j = 0; j < 8; j++) {
                c[kk][j]  = fmaf(F, c[kk][j],  (float)uf[kk][j]);
                nn[kk][j] = fmaf(F, nn[kk][j], un[kk][j]);
            }
    }
    if (w == 0) {
#pragma unroll
        for (int kk = 0; kk < 4; kk++)
#pragma unroll
            for (int j = 0; j < 8; j++) {
                const int dq = kk * 32 + (l >> 4) * 8 + j;
                Cf[((size_t)bh * 128 + dq) * 256 + dv] = c[kk][j];
            }
        if (vt == 0 && (l & 15) == 0) {
#pragma unroll
            for (int kk = 0; kk < 4; kk++)
#pragma unroll
                for (int j = 0; j < 8; j++) {
                    const int dq = kk * 32 + (l >> 4) * 8 + j;
                    nf[(size_t)bh * 128 + dq] = nn[kk][j];
                }
        }
    }
}

// ---------------- per-head layernorm * gamma * sigmoid(og), f16 in/out ----------------
__global__ __launch_bounds__(256) void norm_kernel(const f16* __restrict__ hbuf,
                                                   const f16* __restrict__ qkvo,
                                                   const float* __restrict__ gamma,
                                                   f16* __restrict__ hout) {
    const int row = blockIdx.x;
    const int tid = threadIdx.x;
    const int g = tid >> 5;
    const int l = tid & 31;
    const f16* hrow = hbuf + (size_t)row * D_MODEL + g * 256 + l * 8;
    f16x8 hv8 = *reinterpret_cast<const f16x8*>(hrow);
    float hv[8];
#pragma unroll
    for (int e = 0; e < 8; e++) hv[e] = (float)hv8[e];
    float s = 0.f, s2 = 0.f;
#pragma unroll
    for (int e = 0; e < 8; e++) { s += hv[e]; s2 += hv[e] * hv[e]; }
#pragma unroll
    for (int off = 1; off < 32; off <<= 1) {
        s  += __shfl_xor(s, off);
        s2 += __shfl_xor(s2, off);
    }
    const float mu  = s * (1.f / 256.f);
    const float var = s2 * (1.f / 256.f) - mu * mu;
    const float rs  = rsqrtf(var + 1e-6f);
    const f16* ogr = qkvo + (size_t)row * NCOL + OGOFF + g * 256 + l * 8;
    f16x8 og8 = *reinterpret_cast<const f16x8*>(ogr);
    const float* gam = gamma + g * 256 + l * 8;
    f16x8 o;
#pragma unroll
    for (int e = 0; e < 8; e++) {
        const float og  = (float)og8[e];
        const float sig = __builtin_amdgcn_rcpf(1.f + __expf(-og));
        const float hn  = (hv[e] - mu) * rs * gam[e];
        o[e] = (f16)(sig * hn);
    }
    *reinterpret_cast<f16x8*>(&hout[(size_t)row * D_MODEL + g * 256 + l * 8]) = o;
}

// ---------------- launch ----------------
extern "C" void kernel_launch(void* const* d_in, const int* in_sizes, int n_in,
                              void* d_out, int out_size, void* d_ws, size_t ws_size,
                              hipStream_t stream) {
    (void)in_sizes; (void)n_in; (void)out_size; (void)ws_size;
    const float* x     = (const float*)d_in[0];
    const float* Wq    = (const float*)d_in[1];
    const float* Wk    = (const float*)d_in[2];
    const float* Wv    = (const float*)d_in[3];
    const float* Wog   = (const float*)d_in[4];
    const float* Wig   = (const float*)d_in[5];
    const float* big   = (const float*)d_in[6];
    const float* Wfg   = (const float*)d_in[7];
    const float* bfg   = (const float*)d_in[8];
    const float* gamma = (const float*)d_in[9];
    const float* Wout  = (const float*)d_in[10];

    char* ws = (char*)d_ws;
    size_t off = 0;
    f16*    xf     = (f16*)(ws + off);    off += (size_t)NROWS * D_MODEL * 2;
    f16*    wcat   = (f16*)(ws + off);    off += (size_t)NCOL * D_MODEL * 2;
    f16*    woutf  = (f16*)(ws + off);    off += (size_t)D_MODEL * D_MODEL * 2;
    f16*    qkvo   = (f16*)(ws + off);    off += (size_t)NROWS * NCOL * 2;
    float4* gs4    = (float4*)(ws + off); off += (size_t)16 * S_LEN * 16;
    float2* gchunk = (float2*)(ws + off); off += (size_t)16 * NCHUNK * 8;
    float*  qn_i   = (float*)(ws + off);  off += (size_t)16 * S_LEN * 4;
    float*  UnB    = (float*)(ws + off);  off += (size_t)16 * NCHUNK * 128 * 4;
    f16*    Ubuf   = (f16*)(ws + off);    off += (size_t)16 * NCHUNK * 256 * 128 * 2;
    f16*    hinT   = (f16*)(ws + off);    off += (size_t)16 * 256 * S_LEN * 2;
    f16*    hbuf   = (f16*)(ws + off);    off += (size_t)NROWS * D_MODEL * 2;
    f16*    houtf  = xf;  // xf dead after GEMM1

    float* y  = (float*)d_out;
    float* Cf = y + (size_t)NROWS * D_MODEL;
    float* nf = Cf + (size_t)16 * 128 * 256;
    float* mf = nf + (size_t)16 * 128;

    // fused casts (x + all weights incl. Wig/Wfg into wcat rows 6144..6159)
    cast_all<<<24608, 256, 0, stream>>>(x, Wq, Wk, Wv, Wog, Wig, Wfg, Wout, xf, wcat, woutf);

    // fused qkvo+gates projection (f16 out); q columns pre-scaled by DQ^-0.5.
    // grid.x padded 49 -> 56 (multiple of 8): XCD = x%8 invariant in y, B stays L2-resident.
    gemm_f16<f16><<<dim3(56, NROWS / 128), 256, 0, stream>>>(
        xf, wcat, qkvo, NROWS, NCOL, D_MODEL, NCOL, 1024, 0.08838834764831845f);

    // gate chunk decomposition (reads fused preacts)
    gate_scan<<<16, 256, 0, stream>>>(qkvo, big, bfg, gs4, gchunk, mf);

    // chunkwise mLSTM
    phaseA<<<512, 256, 0, stream>>>(qkvo, gs4, qn_i, Ubuf, hinT, UnB);
    phaseB<<<256, 256, 0, stream>>>(qkvo, Ubuf, hinT, gs4, gchunk, qn_i, UnB, hbuf, Cf, nf);

    // multihead norm + output gate
    norm_kernel<<<NROWS, 256, 0, stream>>>(hbuf, qkvo, gamma, houtf);

    // y = h_out @ Wout^T
    gemm_f16<float><<<dim3(D_MODEL / 128, NROWS / 128), 256, 0, stream>>>(
        houtf, woutf, y, NROWS, D_MODEL, D_MODEL, D_MODEL, 0, 1.f);
}